// Round 3
// baseline (6742.589 us; speedup 1.0000x reference)
//
#include <hip/hip_runtime.h>

#define NN 50000
#define NE 600000
#define DIM 128
#define KD 384   // K*DIM

__global__ void k_zero(float* __restrict__ p, int n4) {
    int i = blockIdx.x * 256 + threadIdx.x;
    if (i < n4) ((float4*)p)[i] = make_float4(0.f, 0.f, 0.f, 0.f);
}

__global__ void k_init_deg(float* __restrict__ deg) {
    int i = blockIdx.x * 256 + threadIdx.x;
    if (i < NN) deg[i] = 1.0f;   // self-loop
}

__global__ void k_hist(const int* __restrict__ dst, float* __restrict__ deg) {
    int e = blockIdx.x * 256 + threadIdx.x;
    if (e < NE) atomicAdd(&deg[dst[e]], 1.0f);
}

__global__ void k_dinv(float* __restrict__ deg) {
    int i = blockIdx.x * 256 + threadIdx.x;
    if (i < NN) deg[i] = rsqrtf(deg[i]);   // deg >= 1 (self-loop)
}

__global__ void k_edgew(const int* __restrict__ src, const int* __restrict__ dst,
                        const float* __restrict__ dinv, float* __restrict__ we) {
    int e = blockIdx.x * 256 + threadIdx.x;
    if (e < NE) we[e] = dinv[src[e]] * dinv[dst[e]];
}

__global__ void k_feat(const float* __restrict__ w, const float* __restrict__ lw,
                       const float* __restrict__ lb, float* __restrict__ A) {
    int i = blockIdx.x * 256 + threadIdx.x;
    if (i < NN * DIM) {
        int n = i >> 7, d = i & 127;
        A[i] = w[n] * lw[d] + lb[d];
    }
}

// S[dst] += w_e * x[src]   (32 threads per edge, float4 per thread)
__global__ void k_scatter(const float* __restrict__ x, const float* __restrict__ we,
                          const int* __restrict__ src, const int* __restrict__ dst,
                          float* __restrict__ S) {
    int t = blockIdx.x * 256 + threadIdx.x;
    int e = t >> 5;
    if (e >= NE) return;
    int lane = t & 31;
    int s = src[e], d = dst[e];
    float w = we[e];
    float4 v = ((const float4*)(x + (size_t)s * DIM))[lane];
    float* o = S + (size_t)d * DIM + lane * 4;
    atomicAdd(o + 0, w * v.x);
    atomicAdd(o + 1, w * v.y);
    atomicAdd(o + 2, w * v.z);
    atomicAdd(o + 3, w * v.w);
}

// In-place: S <- -(S + X/deg)   (self-loop fused: dinv^2 = 1/deg)
__global__ void k_comb1(float* __restrict__ S, const float* __restrict__ X,
                        const float* __restrict__ dinv) {
    int i4 = blockIdx.x * 256 + threadIdx.x;
    if (i4 >= NN * DIM / 4) return;
    float id = dinv[i4 >> 5]; id *= id;
    float4 s = ((const float4*)S)[i4];
    float4 x = ((const float4*)X)[i4];
    float4 r;
    r.x = -(s.x + x.x * id); r.y = -(s.y + x.y * id);
    r.z = -(s.z + x.z * id); r.w = -(s.w + x.w * id);
    ((float4*)S)[i4] = r;
}

// In-place: R <- -2*(R + X1/deg) - X0
__global__ void k_comb2(float* __restrict__ R, const float* __restrict__ X1,
                        const float* __restrict__ X0, const float* __restrict__ dinv) {
    int i4 = blockIdx.x * 256 + threadIdx.x;
    if (i4 >= NN * DIM / 4) return;
    float id = dinv[i4 >> 5]; id *= id;
    float4 s  = ((const float4*)R)[i4];
    float4 x1 = ((const float4*)X1)[i4];
    float4 x0 = ((const float4*)X0)[i4];
    float4 r;
    r.x = -2.f * (s.x + x1.x * id) - x0.x;
    r.y = -2.f * (s.y + x1.y * id) - x0.y;
    r.z = -2.f * (s.z + x1.z * id) - x0.z;
    r.w = -2.f * (s.w + x1.w * id) - x0.w;
    ((float4*)R)[i4] = r;
}

// out = relu([X0|X1|X2] @ W + bias); 16 nodes/block, thread = (2 nodes, 4 cols)
// out may alias X0/X1/X2: each block stages its 16 rows in LDS before writing them.
__global__ __launch_bounds__(256) void k_gemm(
        const float* __restrict__ X0, const float* __restrict__ X1,
        const float* __restrict__ X2, const float* __restrict__ W,
        const float* __restrict__ bias, float* __restrict__ out) {
    __shared__ float4 Xs4[16 * 96];   // [node][384 floats] as float4
    int tid = threadIdx.x;
    int nbase = blockIdx.x * 16;
#pragma unroll
    for (int r = 0; r < 6; ++r) {
        int id = tid + r * 256;          // 0..1535
        int node = id / 96;
        int kq = id - node * 96;         // float4 index within row
        int part = kq >> 5;              // 0:X0 1:X1 2:X2
        int ko = kq & 31;
        const float* base = (part == 0) ? X0 : ((part == 1) ? X1 : X2);
        Xs4[id] = ((const float4*)(base + (size_t)(nbase + node) * DIM))[ko];
    }
    __syncthreads();
    const float* Xs = (const float*)Xs4;
    int jg = tid & 31;      // output col group (4 cols)
    int slot = tid >> 5;    // 0..7 -> 2 nodes each
    const float* xr0 = Xs + (size_t)(slot * 2) * KD;
    const float* xr1 = xr0 + KD;
    const float4* W4 = (const float4*)W;
    float4 acc0 = make_float4(0.f, 0.f, 0.f, 0.f);
    float4 acc1 = make_float4(0.f, 0.f, 0.f, 0.f);
#pragma unroll 4
    for (int k = 0; k < KD; ++k) {
        float4 w = W4[k * 32 + jg];
        float a = xr0[k], b = xr1[k];
        acc0.x = fmaf(a, w.x, acc0.x); acc0.y = fmaf(a, w.y, acc0.y);
        acc0.z = fmaf(a, w.z, acc0.z); acc0.w = fmaf(a, w.w, acc0.w);
        acc1.x = fmaf(b, w.x, acc1.x); acc1.y = fmaf(b, w.y, acc1.y);
        acc1.z = fmaf(b, w.z, acc1.z); acc1.w = fmaf(b, w.w, acc1.w);
    }
    float4 bb = ((const float4*)bias)[jg];
    float4 o0, o1;
    o0.x = fmaxf(acc0.x + bb.x, 0.f); o0.y = fmaxf(acc0.y + bb.y, 0.f);
    o0.z = fmaxf(acc0.z + bb.z, 0.f); o0.w = fmaxf(acc0.w + bb.w, 0.f);
    o1.x = fmaxf(acc1.x + bb.x, 0.f); o1.y = fmaxf(acc1.y + bb.y, 0.f);
    o1.z = fmaxf(acc1.z + bb.z, 0.f); o1.w = fmaxf(acc1.w + bb.w, 0.f);
    int n0 = nbase + slot * 2;
    ((float4*)(out + (size_t)n0 * DIM))[jg] = o0;
    ((float4*)(out + (size_t)(n0 + 1) * DIM))[jg] = o1;
}

// logits[n] = emb[n] . pred_w + pred_b ; one 64-lane wave per node
__global__ void k_predict(const float* __restrict__ emb, const float* __restrict__ pw,
                          const float* __restrict__ pb, float* __restrict__ out) {
    int t = blockIdx.x * 256 + threadIdx.x;
    int n = t >> 6;
    if (n >= NN) return;
    int lane = t & 63;
    const float* row = emb + (size_t)n * DIM;
    float v = row[lane] * pw[lane] + row[lane + 64] * pw[lane + 64];
#pragma unroll
    for (int off = 32; off > 0; off >>= 1) v += __shfl_down(v, off, 64);
    if (lane == 0) out[n] = v + pb[0];
}

extern "C" void kernel_launch(void* const* d_in, const int* in_sizes, int n_in,
                              void* d_out, int out_size, void* d_ws, size_t ws_size,
                              hipStream_t stream) {
    // Locate inputs by element count (ties resolved by occurrence order):
    // weights:50000  src:600000  dst:600000  lin_in_w:128  lin_in_b:128
    // cheb_ws:147456 cheb_bs:384 pred_w:128  pred_b:1
    int i_weights = 0, i_src = 1, i_dst = 2, i_lw = 3, i_lb = 4,
        i_cw = 5, i_cb = 6, i_pw = 7, i_pb = 8;
    {
        int seen600k = 0, seen128 = 0;
        for (int i = 0; i < n_in; ++i) {
            int s = in_sizes[i];
            if (s == 50000) i_weights = i;
            else if (s == 600000) { if (seen600k == 0) i_src = i; else i_dst = i; ++seen600k; }
            else if (s == 128) { if (seen128 == 0) i_lw = i; else if (seen128 == 1) i_lb = i; else i_pw = i; ++seen128; }
            else if (s == 147456) i_cw = i;
            else if (s == 384) i_cb = i;
            else if (s == 1) i_pb = i;
        }
    }
    const float* weights = (const float*)d_in[i_weights];
    const int*   src     = (const int*)d_in[i_src];
    const int*   dst     = (const int*)d_in[i_dst];
    const float* lin_w   = (const float*)d_in[i_lw];
    const float* lin_b   = (const float*)d_in[i_lb];
    const float* cheb_w  = (const float*)d_in[i_cw];
    const float* cheb_b  = (const float*)d_in[i_cb];
    const float* pred_w  = (const float*)d_in[i_pw];
    const float* pred_b  = (const float*)d_in[i_pb];
    float* out = (float*)d_out;

    float* ws   = (float*)d_ws;
    float* dinv = ws;                       // 50000
    float* we   = dinv + 50000;             // 600000
    float* P    = we + 600000;              // 3 big buffers, 6.4M floats each
    float* Q    = P + (size_t)NN * DIM;
    float* R    = Q + (size_t)NN * DIM;
    const int NF4 = NN * DIM / 4;           // 1.6M float4

    k_init_deg<<<196, 256, 0, stream>>>(dinv);
    k_hist<<<2344, 256, 0, stream>>>(dst, dinv);
    k_dinv<<<196, 256, 0, stream>>>(dinv);
    k_edgew<<<2344, 256, 0, stream>>>(src, dst, dinv, we);
    k_feat<<<25000, 256, 0, stream>>>(weights, lin_w, lin_b, P);

    for (int l = 0; l < 3; ++l) {
        // X1 in Q:
        k_zero<<<6250, 256, 0, stream>>>(Q, NF4);
        k_scatter<<<75000, 256, 0, stream>>>(P, we, src, dst, Q);
        k_comb1<<<6250, 256, 0, stream>>>(Q, P, dinv);         // Q = -(spmm(P))
        // X2 in R:
        k_zero<<<6250, 256, 0, stream>>>(R, NF4);
        k_scatter<<<75000, 256, 0, stream>>>(Q, we, src, dst, R);
        k_comb2<<<6250, 256, 0, stream>>>(R, Q, P, dinv);      // R = -2*spmm(Q) - P
        // P = relu([P|Q|R] @ W_l + b_l)   (block-local aliasing, safe)
        k_gemm<<<3125, 256, 0, stream>>>(P, Q, R, cheb_w + (size_t)l * KD * DIM,
                                         cheb_b + (size_t)l * DIM, P);
    }
    k_predict<<<12500, 256, 0, stream>>>(P, pred_w, pred_b, out);
}

// Round 4
// 1097.825 us; speedup vs baseline: 6.1418x; 6.1418x over previous
//
#include <hip/hip_runtime.h>

#define NN 50000
#define NE 600000
#define DIM 128
#define KD 384   // K*DIM

__global__ void k_zero(float* __restrict__ p, int n4) {
    int i = blockIdx.x * 256 + threadIdx.x;
    if (i < n4) ((float4*)p)[i] = make_float4(0.f, 0.f, 0.f, 0.f);
}

__global__ void k_hist(const int* __restrict__ dst, int* __restrict__ cnt) {
    int e = blockIdx.x * 256 + threadIdx.x;
    if (e < NE) atomicAdd(&cnt[dst[e]], 1);
}

__global__ void k_dinv(const int* __restrict__ cnt, float* __restrict__ dinv) {
    int i = blockIdx.x * 256 + threadIdx.x;
    if (i < NN) dinv[i] = rsqrtf((float)(cnt[i] + 1));   // +1 self-loop
}

// Block-level inclusive scan of cnt -> incl, per-block totals -> bsums
__global__ __launch_bounds__(256) void k_scan1(const int* __restrict__ cnt,
                                               int* __restrict__ incl,
                                               int* __restrict__ bsums) {
    __shared__ int sh[256];
    int i = blockIdx.x * 256 + threadIdx.x;
    int v = (i < NN) ? cnt[i] : 0;
    sh[threadIdx.x] = v;
    __syncthreads();
    for (int d = 1; d < 256; d <<= 1) {
        int t = (threadIdx.x >= d) ? sh[threadIdx.x - d] : 0;
        __syncthreads();
        sh[threadIdx.x] += t;
        __syncthreads();
    }
    incl[i] = sh[threadIdx.x];
    if (threadIdx.x == 255) bsums[blockIdx.x] = sh[255];
}

// Exclusive scan of the 196 block sums (single block)
__global__ __launch_bounds__(256) void k_scan2(int* __restrict__ bsums) {
    __shared__ int sh[256];
    int v = (threadIdx.x < 196) ? bsums[threadIdx.x] : 0;
    sh[threadIdx.x] = v;
    __syncthreads();
    for (int d = 1; d < 256; d <<= 1) {
        int t = (threadIdx.x >= d) ? sh[threadIdx.x - d] : 0;
        __syncthreads();
        sh[threadIdx.x] += t;
        __syncthreads();
    }
    if (threadIdx.x < 196) bsums[threadIdx.x] = sh[threadIdx.x] - v;  // exclusive
}

// offs[i] = cursor[i] = global exclusive scan; offs[NN] = NE
__global__ void k_scan3(const int* __restrict__ cnt, int* __restrict__ incl_cursor,
                        const int* __restrict__ bsums, int* __restrict__ offs) {
    int i = blockIdx.x * 256 + threadIdx.x;
    if (i >= NN) return;
    int excl = incl_cursor[i] - cnt[i] + bsums[blockIdx.x];
    offs[i] = excl;
    incl_cursor[i] = excl;   // becomes the fill cursor (same index read->write, safe)
    if (i == NN - 1) offs[NN] = NE;
}

__global__ void k_fill(const int* __restrict__ src, const int* __restrict__ dst,
                       int* __restrict__ cursor, int* __restrict__ csr_src) {
    int e = blockIdx.x * 256 + threadIdx.x;
    if (e < NE) {
        int p = atomicAdd(&cursor[dst[e]], 1);
        csr_src[p] = src[e];
    }
}

__global__ void k_feat(const float* __restrict__ w, const float* __restrict__ lw,
                       const float* __restrict__ lb, float* __restrict__ A) {
    int i = blockIdx.x * 256 + threadIdx.x;
    if (i < NN * DIM) {
        int n = i >> 7, d = i & 127;
        A[i] = w[n] * lw[d] + lb[d];
    }
}

// One 64-lane wave per node (4 nodes/block); lane owns dims {lane, lane+64}.
// Q[n] = -( sum_{e in in(n)} w_e * X[src_e] + X[n]/deg[n] )
__global__ __launch_bounds__(256) void k_gather1(
        const float* __restrict__ X, const int* __restrict__ offs,
        const int* __restrict__ csr_src, const float* __restrict__ dinv,
        float* __restrict__ Q) {
    int n = blockIdx.x * 4 + (threadIdx.x >> 6);   // NN % 4 == 0, grid exact
    int lane = threadIdx.x & 63;
    int j0 = offs[n], j1 = offs[n + 1];
    float dn = dinv[n];
    float a0 = 0.f, a1 = 0.f;
    for (int j = j0; j < j1; ++j) {
        int s = csr_src[j];
        float w = dinv[s] * dn;
        const float* xr = X + (size_t)s * DIM;
        a0 = fmaf(w, xr[lane], a0);
        a1 = fmaf(w, xr[lane + 64], a1);
    }
    float id = dn * dn;
    const float* xn = X + (size_t)n * DIM;
    float* qn = Q + (size_t)n * DIM;
    qn[lane]      = -(a0 + xn[lane] * id);
    qn[lane + 64] = -(a1 + xn[lane + 64] * id);
}

// R[n] = -2*( sum w_e * X1[src_e] + X1[n]/deg[n] ) - X0[n]
__global__ __launch_bounds__(256) void k_gather2(
        const float* __restrict__ X1, const float* __restrict__ X0,
        const int* __restrict__ offs, const int* __restrict__ csr_src,
        const float* __restrict__ dinv, float* __restrict__ R) {
    int n = blockIdx.x * 4 + (threadIdx.x >> 6);
    int lane = threadIdx.x & 63;
    int j0 = offs[n], j1 = offs[n + 1];
    float dn = dinv[n];
    float a0 = 0.f, a1 = 0.f;
    for (int j = j0; j < j1; ++j) {
        int s = csr_src[j];
        float w = dinv[s] * dn;
        const float* xr = X1 + (size_t)s * DIM;
        a0 = fmaf(w, xr[lane], a0);
        a1 = fmaf(w, xr[lane + 64], a1);
    }
    float id = dn * dn;
    const float* x1n = X1 + (size_t)n * DIM;
    const float* x0n = X0 + (size_t)n * DIM;
    float* rn = R + (size_t)n * DIM;
    rn[lane]      = -2.f * (a0 + x1n[lane] * id) - x0n[lane];
    rn[lane + 64] = -2.f * (a1 + x1n[lane + 64] * id) - x0n[lane + 64];
}

// out = relu([X0|X1|X2] @ W + bias); 16 nodes/block, thread = (2 nodes, 4 cols)
// out may alias X0/X1/X2: each block stages its 16 rows in LDS before writing them.
__global__ __launch_bounds__(256) void k_gemm(
        const float* __restrict__ X0, const float* __restrict__ X1,
        const float* __restrict__ X2, const float* __restrict__ W,
        const float* __restrict__ bias, float* __restrict__ out) {
    __shared__ float4 Xs4[16 * 96];   // [node][384 floats] as float4
    int tid = threadIdx.x;
    int nbase = blockIdx.x * 16;
#pragma unroll
    for (int r = 0; r < 6; ++r) {
        int id = tid + r * 256;          // 0..1535
        int node = id / 96;
        int kq = id - node * 96;         // float4 index within row
        int part = kq >> 5;              // 0:X0 1:X1 2:X2
        int ko = kq & 31;
        const float* base = (part == 0) ? X0 : ((part == 1) ? X1 : X2);
        Xs4[id] = ((const float4*)(base + (size_t)(nbase + node) * DIM))[ko];
    }
    __syncthreads();
    const float* Xs = (const float*)Xs4;
    int jg = tid & 31;      // output col group (4 cols)
    int slot = tid >> 5;    // 0..7 -> 2 nodes each
    const float* xr0 = Xs + (size_t)(slot * 2) * KD;
    const float* xr1 = xr0 + KD;
    const float4* W4 = (const float4*)W;
    float4 acc0 = make_float4(0.f, 0.f, 0.f, 0.f);
    float4 acc1 = make_float4(0.f, 0.f, 0.f, 0.f);
#pragma unroll 4
    for (int k = 0; k < KD; ++k) {
        float4 w = W4[k * 32 + jg];
        float a = xr0[k], b = xr1[k];
        acc0.x = fmaf(a, w.x, acc0.x); acc0.y = fmaf(a, w.y, acc0.y);
        acc0.z = fmaf(a, w.z, acc0.z); acc0.w = fmaf(a, w.w, acc0.w);
        acc1.x = fmaf(b, w.x, acc1.x); acc1.y = fmaf(b, w.y, acc1.y);
        acc1.z = fmaf(b, w.z, acc1.z); acc1.w = fmaf(b, w.w, acc1.w);
    }
    float4 bb = ((const float4*)bias)[jg];
    float4 o0, o1;
    o0.x = fmaxf(acc0.x + bb.x, 0.f); o0.y = fmaxf(acc0.y + bb.y, 0.f);
    o0.z = fmaxf(acc0.z + bb.z, 0.f); o0.w = fmaxf(acc0.w + bb.w, 0.f);
    o1.x = fmaxf(acc1.x + bb.x, 0.f); o1.y = fmaxf(acc1.y + bb.y, 0.f);
    o1.z = fmaxf(acc1.z + bb.z, 0.f); o1.w = fmaxf(acc1.w + bb.w, 0.f);
    int n0 = nbase + slot * 2;
    ((float4*)(out + (size_t)n0 * DIM))[jg] = o0;
    ((float4*)(out + (size_t)(n0 + 1) * DIM))[jg] = o1;
}

// logits[n] = emb[n] . pred_w + pred_b ; one 64-lane wave per node
__global__ void k_predict(const float* __restrict__ emb, const float* __restrict__ pw,
                          const float* __restrict__ pb, float* __restrict__ out) {
    int t = blockIdx.x * 256 + threadIdx.x;
    int n = t >> 6;
    if (n >= NN) return;
    int lane = t & 63;
    const float* row = emb + (size_t)n * DIM;
    float v = row[lane] * pw[lane] + row[lane + 64] * pw[lane + 64];
#pragma unroll
    for (int off = 32; off > 0; off >>= 1) v += __shfl_down(v, off, 64);
    if (lane == 0) out[n] = v + pb[0];
}

extern "C" void kernel_launch(void* const* d_in, const int* in_sizes, int n_in,
                              void* d_out, int out_size, void* d_ws, size_t ws_size,
                              hipStream_t stream) {
    // Locate inputs by element count (ties resolved by occurrence order).
    int i_weights = 0, i_src = 1, i_dst = 2, i_lw = 3, i_lb = 4,
        i_cw = 5, i_cb = 6, i_pw = 7, i_pb = 8;
    {
        int seen600k = 0, seen128 = 0;
        for (int i = 0; i < n_in; ++i) {
            int s = in_sizes[i];
            if (s == 50000) i_weights = i;
            else if (s == 600000) { if (seen600k == 0) i_src = i; else i_dst = i; ++seen600k; }
            else if (s == 128) { if (seen128 == 0) i_lw = i; else if (seen128 == 1) i_lb = i; else i_pw = i; ++seen128; }
            else if (s == 147456) i_cw = i;
            else if (s == 384) i_cb = i;
            else if (s == 1) i_pb = i;
        }
    }
    const float* weights = (const float*)d_in[i_weights];
    const int*   src     = (const int*)d_in[i_src];
    const int*   dst     = (const int*)d_in[i_dst];
    const float* lin_w   = (const float*)d_in[i_lw];
    const float* lin_b   = (const float*)d_in[i_lb];
    const float* cheb_w  = (const float*)d_in[i_cw];
    const float* cheb_b  = (const float*)d_in[i_cb];
    const float* pred_w  = (const float*)d_in[i_pw];
    const float* pred_b  = (const float*)d_in[i_pb];
    float* out = (float*)d_out;

    // Workspace layout (79.6 MB total, same footprint as the passing round):
    float* ws      = (float*)d_ws;
    float* dinv    = ws;                         // 50000 (pad to 50048)
    int*   offs    = (int*)(ws + 50048);         // 50001 (pad to 50056)
    int*   csr_src = offs + 50056;               // 600000
    float* P       = (float*)(csr_src + 600000); // 16B-aligned; 6.4M floats
    float* Q       = P + (size_t)NN * DIM;
    float* R       = Q + (size_t)NN * DIM;
    // Scan temporaries alias P (P is written by k_feat only AFTER k_fill):
    int* cnt   = (int*)P;          // 50176
    int* incl  = cnt + 50176;      // 50176 (becomes the fill cursor)
    int* bsums = incl + 50176;     // 256

    // --- CSR build (once) ---
    k_zero<<<49, 256, 0, stream>>>((float*)cnt, 12544);      // 50176 ints
    k_hist<<<2344, 256, 0, stream>>>(dst, cnt);
    k_dinv<<<196, 256, 0, stream>>>(cnt, dinv);
    k_scan1<<<196, 256, 0, stream>>>(cnt, incl, bsums);
    k_scan2<<<1, 256, 0, stream>>>(bsums);
    k_scan3<<<196, 256, 0, stream>>>(cnt, incl, bsums, offs);
    k_fill<<<2344, 256, 0, stream>>>(src, dst, incl, csr_src);

    // --- network ---
    k_feat<<<25000, 256, 0, stream>>>(weights, lin_w, lin_b, P);
    for (int l = 0; l < 3; ++l) {
        k_gather1<<<12500, 256, 0, stream>>>(P, offs, csr_src, dinv, Q);
        k_gather2<<<12500, 256, 0, stream>>>(Q, P, offs, csr_src, dinv, R);
        k_gemm<<<3125, 256, 0, stream>>>(P, Q, R, cheb_w + (size_t)l * KD * DIM,
                                         cheb_b + (size_t)l * DIM, P);
    }
    k_predict<<<12500, 256, 0, stream>>>(P, pred_w, pred_b, out);
}

// Round 5
// 814.804 us; speedup vs baseline: 8.2751x; 1.3473x over previous
//
#include <hip/hip_runtime.h>

#define NN 50000
#define NE 600000
#define DIM 128
#define KD 384   // K*DIM

__global__ void k_zero(float* __restrict__ p, int n4) {
    int i = blockIdx.x * 256 + threadIdx.x;
    if (i < n4) ((float4*)p)[i] = make_float4(0.f, 0.f, 0.f, 0.f);
}

__global__ void k_hist(const int* __restrict__ dst, int* __restrict__ cnt) {
    int e = blockIdx.x * 256 + threadIdx.x;
    if (e < NE) atomicAdd(&cnt[dst[e]], 1);
}

__global__ void k_dinv(const int* __restrict__ cnt, float* __restrict__ dinv) {
    int i = blockIdx.x * 256 + threadIdx.x;
    if (i < NN) dinv[i] = rsqrtf((float)(cnt[i] + 1));   // +1 self-loop
}

// Block-level inclusive scan of cnt -> incl, per-block totals -> bsums
__global__ __launch_bounds__(256) void k_scan1(const int* __restrict__ cnt,
                                               int* __restrict__ incl,
                                               int* __restrict__ bsums) {
    __shared__ int sh[256];
    int i = blockIdx.x * 256 + threadIdx.x;
    int v = (i < NN) ? cnt[i] : 0;
    sh[threadIdx.x] = v;
    __syncthreads();
    for (int d = 1; d < 256; d <<= 1) {
        int t = (threadIdx.x >= d) ? sh[threadIdx.x - d] : 0;
        __syncthreads();
        sh[threadIdx.x] += t;
        __syncthreads();
    }
    incl[i] = sh[threadIdx.x];
    if (threadIdx.x == 255) bsums[blockIdx.x] = sh[255];
}

__global__ __launch_bounds__(256) void k_scan2(int* __restrict__ bsums) {
    __shared__ int sh[256];
    int v = (threadIdx.x < 196) ? bsums[threadIdx.x] : 0;
    sh[threadIdx.x] = v;
    __syncthreads();
    for (int d = 1; d < 256; d <<= 1) {
        int t = (threadIdx.x >= d) ? sh[threadIdx.x - d] : 0;
        __syncthreads();
        sh[threadIdx.x] += t;
        __syncthreads();
    }
    if (threadIdx.x < 196) bsums[threadIdx.x] = sh[threadIdx.x] - v;  // exclusive
}

__global__ void k_scan3(const int* __restrict__ cnt, int* __restrict__ incl_cursor,
                        const int* __restrict__ bsums, int* __restrict__ offs) {
    int i = blockIdx.x * 256 + threadIdx.x;
    if (i >= NN) return;
    int excl = incl_cursor[i] - cnt[i] + bsums[blockIdx.x];
    offs[i] = excl;
    incl_cursor[i] = excl;   // becomes the fill cursor
    if (i == NN - 1) offs[NN] = NE;
}

__global__ void k_fill(const int* __restrict__ src, const int* __restrict__ dst,
                       int* __restrict__ cursor, int* __restrict__ csr_src) {
    int e = blockIdx.x * 256 + threadIdx.x;
    if (e < NE) {
        int p = atomicAdd(&cursor[dst[e]], 1);
        csr_src[p] = src[e];
    }
}

__global__ void k_feat(const float* __restrict__ w, const float* __restrict__ lw,
                       const float* __restrict__ lb, float* __restrict__ A) {
    int i = blockIdx.x * 256 + threadIdx.x;
    if (i < NN * DIM) {
        int n = i >> 7, d = i & 127;
        A[i] = w[n] * lw[d] + lb[d];
    }
}

// One 64-lane wave per node (4 nodes/block); lane owns dims {lane, lane+64}.
__global__ __launch_bounds__(256) void k_gather1(
        const float* __restrict__ X, const int* __restrict__ offs,
        const int* __restrict__ csr_src, const float* __restrict__ dinv,
        float* __restrict__ Q) {
    int n = blockIdx.x * 4 + (threadIdx.x >> 6);
    int lane = threadIdx.x & 63;
    int j0 = offs[n], j1 = offs[n + 1];
    float dn = dinv[n];
    float a0 = 0.f, a1 = 0.f;
    for (int j = j0; j < j1; ++j) {
        int s = csr_src[j];
        float w = dinv[s] * dn;
        const float* xr = X + (size_t)s * DIM;
        a0 = fmaf(w, xr[lane], a0);
        a1 = fmaf(w, xr[lane + 64], a1);
    }
    float id = dn * dn;
    const float* xn = X + (size_t)n * DIM;
    float* qn = Q + (size_t)n * DIM;
    qn[lane]      = -(a0 + xn[lane] * id);
    qn[lane + 64] = -(a1 + xn[lane + 64] * id);
}

__global__ __launch_bounds__(256) void k_gather2(
        const float* __restrict__ X1, const float* __restrict__ X0,
        const int* __restrict__ offs, const int* __restrict__ csr_src,
        const float* __restrict__ dinv, float* __restrict__ R) {
    int n = blockIdx.x * 4 + (threadIdx.x >> 6);
    int lane = threadIdx.x & 63;
    int j0 = offs[n], j1 = offs[n + 1];
    float dn = dinv[n];
    float a0 = 0.f, a1 = 0.f;
    for (int j = j0; j < j1; ++j) {
        int s = csr_src[j];
        float w = dinv[s] * dn;
        const float* xr = X1 + (size_t)s * DIM;
        a0 = fmaf(w, xr[lane], a0);
        a1 = fmaf(w, xr[lane + 64], a1);
    }
    float id = dn * dn;
    const float* x1n = X1 + (size_t)n * DIM;
    const float* x0n = X0 + (size_t)n * DIM;
    float* rn = R + (size_t)n * DIM;
    rn[lane]      = -2.f * (a0 + x1n[lane] * id) - x0n[lane];
    rn[lane + 64] = -2.f * (a1 + x1n[lane + 64] * id) - x0n[lane + 64];
}

// out = relu([X0|X1|X2] @ W + bias), tiled: 64 nodes x 128 cols per block.
// K-chunks of 32: A-tile transposed (As[k][node], 8KB) + W-tile (Ws[k][col], 16KB).
// Thread = 8 nodes x 4 cols = 32 accumulators. W read from global exactly once/block.
// out may alias X0/X1/X2: each block writes only its own 64 rows, after all its
// global reads of those rows (separated by __syncthreads).
__global__ __launch_bounds__(256) void k_gemm(
        const float* __restrict__ X0, const float* __restrict__ X1,
        const float* __restrict__ X2, const float* __restrict__ W,
        const float* __restrict__ bias, float* __restrict__ out) {
    __shared__ float As[32 * 64];    // [k][node]
    __shared__ float Ws[32 * 128];   // [k][col]
    int tid = threadIdx.x;
    int nbase = blockIdx.x * 64;
    int jg = tid & 31;        // col group (4 cols)
    int rg = tid >> 5;        // node group (8 nodes)
    int rg2 = rg * 2;

    float4 acc[8];
#pragma unroll
    for (int i = 0; i < 8; ++i) acc[i] = make_float4(0.f, 0.f, 0.f, 0.f);

    // A-load mapping: n_a = tid>>2 (0..63), kq_a = tid&3; loads float4 kq_a and kq_a+4
    int n_a = tid >> 2;
    int kq_a = tid & 3;
    int n_ld = nbase + n_a;
    if (n_ld >= NN) n_ld = NN - 1;   // clamp (results discarded at store)

    const float4* W4 = (const float4*)W;
    const float4* Ws4 = (const float4*)Ws;
    const float4* As4 = (const float4*)As;

    for (int c = 0; c < 12; ++c) {
        int part = c >> 2;
        int k0 = (c & 3) * 32;
        const float* Xp = (part == 0) ? X0 : ((part == 1) ? X1 : X2);
        const float4* xrow = (const float4*)(Xp + (size_t)n_ld * DIM + k0);
        float4 a0 = xrow[kq_a];
        float4 a1 = xrow[kq_a + 4];
        const float4* wsrc = W4 + (size_t)c * 1024;   // 32 rows x 32 float4
        float4 w0 = wsrc[tid];
        float4 w1 = wsrc[tid + 256];
        float4 w2 = wsrc[tid + 512];
        float4 w3 = wsrc[tid + 768];
        __syncthreads();   // previous chunk's readers done
        int kk = kq_a * 4;
        As[(kk + 0) * 64 + n_a] = a0.x;
        As[(kk + 1) * 64 + n_a] = a0.y;
        As[(kk + 2) * 64 + n_a] = a0.z;
        As[(kk + 3) * 64 + n_a] = a0.w;
        As[(kk + 16) * 64 + n_a] = a1.x;
        As[(kk + 17) * 64 + n_a] = a1.y;
        As[(kk + 18) * 64 + n_a] = a1.z;
        As[(kk + 19) * 64 + n_a] = a1.w;
        ((float4*)Ws)[tid]       = w0;
        ((float4*)Ws)[tid + 256] = w1;
        ((float4*)Ws)[tid + 512] = w2;
        ((float4*)Ws)[tid + 768] = w3;
        __syncthreads();
#pragma unroll 4
        for (int k = 0; k < 32; ++k) {
            float4 w = Ws4[k * 32 + jg];
            float4 A0 = As4[k * 16 + rg2];
            float4 A1 = As4[k * 16 + rg2 + 1];
            float av[8] = {A0.x, A0.y, A0.z, A0.w, A1.x, A1.y, A1.z, A1.w};
#pragma unroll
            for (int i = 0; i < 8; ++i) {
                acc[i].x = fmaf(av[i], w.x, acc[i].x);
                acc[i].y = fmaf(av[i], w.y, acc[i].y);
                acc[i].z = fmaf(av[i], w.z, acc[i].z);
                acc[i].w = fmaf(av[i], w.w, acc[i].w);
            }
        }
    }

    float4 bb = ((const float4*)bias)[jg];
#pragma unroll
    for (int i = 0; i < 8; ++i) {
        int node = nbase + rg * 8 + i;
        if (node < NN) {
            float4 o;
            o.x = fmaxf(acc[i].x + bb.x, 0.f);
            o.y = fmaxf(acc[i].y + bb.y, 0.f);
            o.z = fmaxf(acc[i].z + bb.z, 0.f);
            o.w = fmaxf(acc[i].w + bb.w, 0.f);
            ((float4*)(out + (size_t)node * DIM))[jg] = o;
        }
    }
}

// logits[n] = emb[n] . pred_w + pred_b ; one 64-lane wave per node
__global__ void k_predict(const float* __restrict__ emb, const float* __restrict__ pw,
                          const float* __restrict__ pb, float* __restrict__ out) {
    int t = blockIdx.x * 256 + threadIdx.x;
    int n = t >> 6;
    if (n >= NN) return;
    int lane = t & 63;
    const float* row = emb + (size_t)n * DIM;
    float v = row[lane] * pw[lane] + row[lane + 64] * pw[lane + 64];
#pragma unroll
    for (int off = 32; off > 0; off >>= 1) v += __shfl_down(v, off, 64);
    if (lane == 0) out[n] = v + pb[0];
}

extern "C" void kernel_launch(void* const* d_in, const int* in_sizes, int n_in,
                              void* d_out, int out_size, void* d_ws, size_t ws_size,
                              hipStream_t stream) {
    int i_weights = 0, i_src = 1, i_dst = 2, i_lw = 3, i_lb = 4,
        i_cw = 5, i_cb = 6, i_pw = 7, i_pb = 8;
    {
        int seen600k = 0, seen128 = 0;
        for (int i = 0; i < n_in; ++i) {
            int s = in_sizes[i];
            if (s == 50000) i_weights = i;
            else if (s == 600000) { if (seen600k == 0) i_src = i; else i_dst = i; ++seen600k; }
            else if (s == 128) { if (seen128 == 0) i_lw = i; else if (seen128 == 1) i_lb = i; else i_pw = i; ++seen128; }
            else if (s == 147456) i_cw = i;
            else if (s == 384) i_cb = i;
            else if (s == 1) i_pb = i;
        }
    }
    const float* weights = (const float*)d_in[i_weights];
    const int*   src     = (const int*)d_in[i_src];
    const int*   dst     = (const int*)d_in[i_dst];
    const float* lin_w   = (const float*)d_in[i_lw];
    const float* lin_b   = (const float*)d_in[i_lb];
    const float* cheb_w  = (const float*)d_in[i_cw];
    const float* cheb_b  = (const float*)d_in[i_cb];
    const float* pred_w  = (const float*)d_in[i_pw];
    const float* pred_b  = (const float*)d_in[i_pb];
    float* out = (float*)d_out;

    float* ws      = (float*)d_ws;
    float* dinv    = ws;                         // 50000 (pad to 50048)
    int*   offs    = (int*)(ws + 50048);         // 50001 (pad to 50056)
    int*   csr_src = offs + 50056;               // 600000
    float* P       = (float*)(csr_src + 600000); // 6.4M floats each
    float* Q       = P + (size_t)NN * DIM;
    float* R       = Q + (size_t)NN * DIM;
    int* cnt   = (int*)P;          // scan temporaries alias P (pre-k_feat)
    int* incl  = cnt + 50176;
    int* bsums = incl + 50176;

    // --- CSR build (once) ---
    k_zero<<<49, 256, 0, stream>>>((float*)cnt, 12544);
    k_hist<<<2344, 256, 0, stream>>>(dst, cnt);
    k_dinv<<<196, 256, 0, stream>>>(cnt, dinv);
    k_scan1<<<196, 256, 0, stream>>>(cnt, incl, bsums);
    k_scan2<<<1, 256, 0, stream>>>(bsums);
    k_scan3<<<196, 256, 0, stream>>>(cnt, incl, bsums, offs);
    k_fill<<<2344, 256, 0, stream>>>(src, dst, incl, csr_src);

    // --- network ---
    k_feat<<<25000, 256, 0, stream>>>(weights, lin_w, lin_b, P);
    for (int l = 0; l < 3; ++l) {
        k_gather1<<<12500, 256, 0, stream>>>(P, offs, csr_src, dinv, Q);
        k_gather2<<<12500, 256, 0, stream>>>(Q, P, offs, csr_src, dinv, R);
        k_gemm<<<782, 256, 0, stream>>>(P, Q, R, cheb_w + (size_t)l * KD * DIM,
                                        cheb_b + (size_t)l * DIM, P);
    }
    k_predict<<<12500, 256, 0, stream>>>(P, pred_w, pred_b, out);
}

// Round 6
// 740.196 us; speedup vs baseline: 9.1092x; 1.1008x over previous
//
#include <hip/hip_runtime.h>

#define NN 50000
#define NE 600000
#define DIM 128
#define KD 384   // K*DIM

__global__ void k_zero(float* __restrict__ p, int n4) {
    int i = blockIdx.x * 256 + threadIdx.x;
    if (i < n4) ((float4*)p)[i] = make_float4(0.f, 0.f, 0.f, 0.f);
}

__global__ void k_hist(const int* __restrict__ dst, int* __restrict__ cnt) {
    int e = blockIdx.x * 256 + threadIdx.x;
    if (e < NE) atomicAdd(&cnt[dst[e]], 1);
}

__global__ void k_dinv(const int* __restrict__ cnt, float* __restrict__ dinv) {
    int i = blockIdx.x * 256 + threadIdx.x;
    if (i < NN) dinv[i] = rsqrtf((float)(cnt[i] + 1));   // +1 self-loop
}

// Block-level inclusive scan of cnt -> incl, per-block totals -> bsums
__global__ __launch_bounds__(256) void k_scan1(const int* __restrict__ cnt,
                                               int* __restrict__ incl,
                                               int* __restrict__ bsums) {
    __shared__ int sh[256];
    int i = blockIdx.x * 256 + threadIdx.x;
    int v = (i < NN) ? cnt[i] : 0;
    sh[threadIdx.x] = v;
    __syncthreads();
    for (int d = 1; d < 256; d <<= 1) {
        int t = (threadIdx.x >= d) ? sh[threadIdx.x - d] : 0;
        __syncthreads();
        sh[threadIdx.x] += t;
        __syncthreads();
    }
    incl[i] = sh[threadIdx.x];
    if (threadIdx.x == 255) bsums[blockIdx.x] = sh[255];
}

__global__ __launch_bounds__(256) void k_scan2(int* __restrict__ bsums) {
    __shared__ int sh[256];
    int v = (threadIdx.x < 196) ? bsums[threadIdx.x] : 0;
    sh[threadIdx.x] = v;
    __syncthreads();
    for (int d = 1; d < 256; d <<= 1) {
        int t = (threadIdx.x >= d) ? sh[threadIdx.x - d] : 0;
        __syncthreads();
        sh[threadIdx.x] += t;
        __syncthreads();
    }
    if (threadIdx.x < 196) bsums[threadIdx.x] = sh[threadIdx.x] - v;  // exclusive
}

__global__ void k_scan3(const int* __restrict__ cnt, int* __restrict__ incl_cursor,
                        const int* __restrict__ bsums, int* __restrict__ offs) {
    int i = blockIdx.x * 256 + threadIdx.x;
    if (i >= NN) return;
    int excl = incl_cursor[i] - cnt[i] + bsums[blockIdx.x];
    offs[i] = excl;
    incl_cursor[i] = excl;   // becomes the fill cursor
    if (i == NN - 1) offs[NN] = NE;
}

__global__ void k_fill(const int* __restrict__ src, const int* __restrict__ dst,
                       int* __restrict__ cursor, int* __restrict__ csr_src) {
    int e = blockIdx.x * 256 + threadIdx.x;
    if (e < NE) {
        int p = atomicAdd(&cursor[dst[e]], 1);
        csr_src[p] = src[e];
    }
}

__global__ void k_feat(const float* __restrict__ w, const float* __restrict__ lw,
                       const float* __restrict__ lb, float* __restrict__ A) {
    int i = blockIdx.x * 256 + threadIdx.x;
    if (i < NN * DIM) {
        int n = i >> 7, d = i & 127;
        A[i] = w[n] * lw[d] + lb[d];
    }
}

// Wave-per-node gather with batched index staging + 4x unrolled row accumulate.
// Lane owns dims {lane, lane+64}. Q[n] = -( sum w_e*X[src] + X[n]/deg )
__global__ __launch_bounds__(256) void k_gather1(
        const float* __restrict__ X, const int* __restrict__ offs,
        const int* __restrict__ csr_src, const float* __restrict__ dinv,
        float* __restrict__ Q) {
    int n = blockIdx.x * 4 + (threadIdx.x >> 6);
    int lane = threadIdx.x & 63;
    int j0 = offs[n], j1 = offs[n + 1];
    float dn = dinv[n];
    float a0 = 0.f, a1 = 0.f;
    for (int base = j0; base < j1; base += 64) {
        int m = j1 - base; if (m > 64) m = 64;
        int s = 0; float wv = 0.f;
        if (lane < m) { s = csr_src[base + lane]; wv = dinv[s] * dn; }
        int t = 0;
        for (; t + 4 <= m; t += 4) {
            int s0 = __shfl(s, t, 64),     s1 = __shfl(s, t + 1, 64);
            int s2 = __shfl(s, t + 2, 64), s3 = __shfl(s, t + 3, 64);
            float w0 = __shfl(wv, t, 64),     w1 = __shfl(wv, t + 1, 64);
            float w2 = __shfl(wv, t + 2, 64), w3 = __shfl(wv, t + 3, 64);
            const float* r0 = X + (size_t)s0 * DIM;
            const float* r1 = X + (size_t)s1 * DIM;
            const float* r2 = X + (size_t)s2 * DIM;
            const float* r3 = X + (size_t)s3 * DIM;
            float x00 = r0[lane], x01 = r0[lane + 64];
            float x10 = r1[lane], x11 = r1[lane + 64];
            float x20 = r2[lane], x21 = r2[lane + 64];
            float x30 = r3[lane], x31 = r3[lane + 64];
            a0 = fmaf(w0, x00, a0); a1 = fmaf(w0, x01, a1);
            a0 = fmaf(w1, x10, a0); a1 = fmaf(w1, x11, a1);
            a0 = fmaf(w2, x20, a0); a1 = fmaf(w2, x21, a1);
            a0 = fmaf(w3, x30, a0); a1 = fmaf(w3, x31, a1);
        }
        for (; t < m; ++t) {
            int ss = __shfl(s, t, 64);
            float ww = __shfl(wv, t, 64);
            const float* r = X + (size_t)ss * DIM;
            a0 = fmaf(ww, r[lane], a0);
            a1 = fmaf(ww, r[lane + 64], a1);
        }
    }
    float id = dn * dn;
    const float* xn = X + (size_t)n * DIM;
    float* qn = Q + (size_t)n * DIM;
    qn[lane]      = -(a0 + xn[lane] * id);
    qn[lane + 64] = -(a1 + xn[lane + 64] * id);
}

// R[n] = -2*( sum w_e*X1[src] + X1[n]/deg ) - X0[n]
__global__ __launch_bounds__(256) void k_gather2(
        const float* __restrict__ X1, const float* __restrict__ X0,
        const int* __restrict__ offs, const int* __restrict__ csr_src,
        const float* __restrict__ dinv, float* __restrict__ R) {
    int n = blockIdx.x * 4 + (threadIdx.x >> 6);
    int lane = threadIdx.x & 63;
    int j0 = offs[n], j1 = offs[n + 1];
    float dn = dinv[n];
    float a0 = 0.f, a1 = 0.f;
    for (int base = j0; base < j1; base += 64) {
        int m = j1 - base; if (m > 64) m = 64;
        int s = 0; float wv = 0.f;
        if (lane < m) { s = csr_src[base + lane]; wv = dinv[s] * dn; }
        int t = 0;
        for (; t + 4 <= m; t += 4) {
            int s0 = __shfl(s, t, 64),     s1 = __shfl(s, t + 1, 64);
            int s2 = __shfl(s, t + 2, 64), s3 = __shfl(s, t + 3, 64);
            float w0 = __shfl(wv, t, 64),     w1 = __shfl(wv, t + 1, 64);
            float w2 = __shfl(wv, t + 2, 64), w3 = __shfl(wv, t + 3, 64);
            const float* r0 = X1 + (size_t)s0 * DIM;
            const float* r1 = X1 + (size_t)s1 * DIM;
            const float* r2 = X1 + (size_t)s2 * DIM;
            const float* r3 = X1 + (size_t)s3 * DIM;
            float x00 = r0[lane], x01 = r0[lane + 64];
            float x10 = r1[lane], x11 = r1[lane + 64];
            float x20 = r2[lane], x21 = r2[lane + 64];
            float x30 = r3[lane], x31 = r3[lane + 64];
            a0 = fmaf(w0, x00, a0); a1 = fmaf(w0, x01, a1);
            a0 = fmaf(w1, x10, a0); a1 = fmaf(w1, x11, a1);
            a0 = fmaf(w2, x20, a0); a1 = fmaf(w2, x21, a1);
            a0 = fmaf(w3, x30, a0); a1 = fmaf(w3, x31, a1);
        }
        for (; t < m; ++t) {
            int ss = __shfl(s, t, 64);
            float ww = __shfl(wv, t, 64);
            const float* r = X1 + (size_t)ss * DIM;
            a0 = fmaf(ww, r[lane], a0);
            a1 = fmaf(ww, r[lane + 64], a1);
        }
    }
    float id = dn * dn;
    const float* x1n = X1 + (size_t)n * DIM;
    const float* x0n = X0 + (size_t)n * DIM;
    float* rn = R + (size_t)n * DIM;
    rn[lane]      = -2.f * (a0 + x1n[lane] * id) - x0n[lane];
    rn[lane + 64] = -2.f * (a1 + x1n[lane + 64] * id) - x0n[lane + 64];
}

// out = relu([X0|X1|X2] @ W + bias), 64 nodes x 128 cols per block, K-chunk 32,
// software-pipelined: chunk c+1 globals prefetched into registers during compute
// of chunk c. Each block reads only its OWN 64 rows of X0/X1/X2, so out may
// alias X0 (writes happen after all that block's reads).
__global__ __launch_bounds__(256) void k_gemm(
        const float* __restrict__ X0, const float* __restrict__ X1,
        const float* __restrict__ X2, const float* __restrict__ W,
        const float* __restrict__ bias, float* __restrict__ out) {
    __shared__ float As[32 * 64];    // [k][node]
    __shared__ float Ws[32 * 128];   // [k][col]
    int tid = threadIdx.x;
    int nbase = blockIdx.x * 64;
    int jg = tid & 31;        // col group (4 cols)
    int rg = tid >> 5;        // node group (8 nodes)
    int rg2 = rg * 2;

    float4 acc[8];
#pragma unroll
    for (int i = 0; i < 8; ++i) acc[i] = make_float4(0.f, 0.f, 0.f, 0.f);

    int n_a = tid >> 2;
    int kq_a = tid & 3;
    int n_ld = nbase + n_a;
    if (n_ld >= NN) n_ld = NN - 1;   // clamp (results discarded at store)

    const float4* W4 = (const float4*)W;
    const float4* Ws4 = (const float4*)Ws;
    const float4* As4 = (const float4*)As;

    float4 cur[6], nxt[6];
    {   // prefetch chunk 0
        const float4* xrow = (const float4*)(X0 + (size_t)n_ld * DIM);
        cur[0] = xrow[kq_a]; cur[1] = xrow[kq_a + 4];
        cur[2] = W4[tid]; cur[3] = W4[tid + 256];
        cur[4] = W4[tid + 512]; cur[5] = W4[tid + 768];
    }
    for (int c = 0; c < 12; ++c) {
        __syncthreads();   // previous chunk's LDS readers done
        int kk = kq_a * 4;
        As[(kk + 0) * 64 + n_a] = cur[0].x;
        As[(kk + 1) * 64 + n_a] = cur[0].y;
        As[(kk + 2) * 64 + n_a] = cur[0].z;
        As[(kk + 3) * 64 + n_a] = cur[0].w;
        As[(kk + 16) * 64 + n_a] = cur[1].x;
        As[(kk + 17) * 64 + n_a] = cur[1].y;
        As[(kk + 18) * 64 + n_a] = cur[1].z;
        As[(kk + 19) * 64 + n_a] = cur[1].w;
        ((float4*)Ws)[tid]       = cur[2];
        ((float4*)Ws)[tid + 256] = cur[3];
        ((float4*)Ws)[tid + 512] = cur[4];
        ((float4*)Ws)[tid + 768] = cur[5];
        __syncthreads();
        if (c + 1 < 12) {   // prefetch next chunk; latency hidden under compute
            int part = (c + 1) >> 2;
            int k0 = ((c + 1) & 3) * 32;
            const float* Xp = (part == 0) ? X0 : ((part == 1) ? X1 : X2);
            const float4* xrow = (const float4*)(Xp + (size_t)n_ld * DIM + k0);
            nxt[0] = xrow[kq_a]; nxt[1] = xrow[kq_a + 4];
            const float4* wsrc = W4 + (size_t)(c + 1) * 1024;
            nxt[2] = wsrc[tid]; nxt[3] = wsrc[tid + 256];
            nxt[4] = wsrc[tid + 512]; nxt[5] = wsrc[tid + 768];
        }
#pragma unroll 4
        for (int k = 0; k < 32; ++k) {
            float4 w = Ws4[k * 32 + jg];
            float4 A0 = As4[k * 16 + rg2];
            float4 A1 = As4[k * 16 + rg2 + 1];
            float av[8] = {A0.x, A0.y, A0.z, A0.w, A1.x, A1.y, A1.z, A1.w};
#pragma unroll
            for (int i = 0; i < 8; ++i) {
                acc[i].x = fmaf(av[i], w.x, acc[i].x);
                acc[i].y = fmaf(av[i], w.y, acc[i].y);
                acc[i].z = fmaf(av[i], w.z, acc[i].z);
                acc[i].w = fmaf(av[i], w.w, acc[i].w);
            }
        }
#pragma unroll
        for (int i = 0; i < 6; ++i) cur[i] = nxt[i];
    }

    float4 bb = ((const float4*)bias)[jg];
#pragma unroll
    for (int i = 0; i < 8; ++i) {
        int node = nbase + rg * 8 + i;
        if (node < NN) {
            float4 o;
            o.x = fmaxf(acc[i].x + bb.x, 0.f);
            o.y = fmaxf(acc[i].y + bb.y, 0.f);
            o.z = fmaxf(acc[i].z + bb.z, 0.f);
            o.w = fmaxf(acc[i].w + bb.w, 0.f);
            ((float4*)(out + (size_t)node * DIM))[jg] = o;
        }
    }
}

// logits[n] = emb[n] . pred_w + pred_b ; one 64-lane wave per node
__global__ void k_predict(const float* __restrict__ emb, const float* __restrict__ pw,
                          const float* __restrict__ pb, float* __restrict__ out) {
    int t = blockIdx.x * 256 + threadIdx.x;
    int n = t >> 6;
    if (n >= NN) return;
    int lane = t & 63;
    const float* row = emb + (size_t)n * DIM;
    float v = row[lane] * pw[lane] + row[lane + 64] * pw[lane + 64];
#pragma unroll
    for (int off = 32; off > 0; off >>= 1) v += __shfl_down(v, off, 64);
    if (lane == 0) out[n] = v + pb[0];
}

extern "C" void kernel_launch(void* const* d_in, const int* in_sizes, int n_in,
                              void* d_out, int out_size, void* d_ws, size_t ws_size,
                              hipStream_t stream) {
    int i_weights = 0, i_src = 1, i_dst = 2, i_lw = 3, i_lb = 4,
        i_cw = 5, i_cb = 6, i_pw = 7, i_pb = 8;
    {
        int seen600k = 0, seen128 = 0;
        for (int i = 0; i < n_in; ++i) {
            int s = in_sizes[i];
            if (s == 50000) i_weights = i;
            else if (s == 600000) { if (seen600k == 0) i_src = i; else i_dst = i; ++seen600k; }
            else if (s == 128) { if (seen128 == 0) i_lw = i; else if (seen128 == 1) i_lb = i; else i_pw = i; ++seen128; }
            else if (s == 147456) i_cw = i;
            else if (s == 384) i_cb = i;
            else if (s == 1) i_pb = i;
        }
    }
    const float* weights = (const float*)d_in[i_weights];
    const int*   src     = (const int*)d_in[i_src];
    const int*   dst     = (const int*)d_in[i_dst];
    const float* lin_w   = (const float*)d_in[i_lw];
    const float* lin_b   = (const float*)d_in[i_lb];
    const float* cheb_w  = (const float*)d_in[i_cw];
    const float* cheb_b  = (const float*)d_in[i_cb];
    const float* pred_w  = (const float*)d_in[i_pw];
    const float* pred_b  = (const float*)d_in[i_pb];
    float* out = (float*)d_out;

    float* ws      = (float*)d_ws;
    float* dinv    = ws;                         // 50000 (pad to 50048)
    int*   offs    = (int*)(ws + 50048);         // 50001 (pad to 50056)
    int*   csr_src = offs + 50056;               // 600000
    float* P       = (float*)(csr_src + 600000); // 6.4M floats each
    float* Q       = P + (size_t)NN * DIM;
    float* R       = Q + (size_t)NN * DIM;
    int* cnt   = (int*)P;          // scan temporaries alias P (pre-k_feat)
    int* incl  = cnt + 50176;
    int* bsums = incl + 50176;

    // --- CSR build (once) ---
    k_zero<<<49, 256, 0, stream>>>((float*)cnt, 12544);
    k_hist<<<2344, 256, 0, stream>>>(dst, cnt);
    k_dinv<<<196, 256, 0, stream>>>(cnt, dinv);
    k_scan1<<<196, 256, 0, stream>>>(cnt, incl, bsums);
    k_scan2<<<1, 256, 0, stream>>>(bsums);
    k_scan3<<<196, 256, 0, stream>>>(cnt, incl, bsums, offs);
    k_fill<<<2344, 256, 0, stream>>>(src, dst, incl, csr_src);

    // --- network ---
    k_feat<<<25000, 256, 0, stream>>>(weights, lin_w, lin_b, P);
    for (int l = 0; l < 3; ++l) {
        k_gather1<<<12500, 256, 0, stream>>>(P, offs, csr_src, dinv, Q);
        k_gather2<<<12500, 256, 0, stream>>>(Q, P, offs, csr_src, dinv, R);
        k_gemm<<<782, 256, 0, stream>>>(P, Q, R, cheb_w + (size_t)l * KD * DIM,
                                        cheb_b + (size_t)l * DIM, P);
    }
    k_predict<<<12500, 256, 0, stream>>>(P, pred_w, pred_b, out);
}

// Round 7
// 694.933 us; speedup vs baseline: 9.7025x; 1.0651x over previous
//
#include <hip/hip_runtime.h>

typedef unsigned int uint;
typedef unsigned short ushort;

#define NN 50000
#define NE 600000
#define DIM 128
#define KD 384   // K*DIM

static __device__ __forceinline__ ushort f2b(float f) {   // fp32 -> bf16 RNE
    uint u = __float_as_uint(f);
    return (ushort)((u + 0x7FFFu + ((u >> 16) & 1u)) >> 16);
}

__global__ void k_zero(float* __restrict__ p, int n4) {
    int i = blockIdx.x * 256 + threadIdx.x;
    if (i < n4) ((float4*)p)[i] = make_float4(0.f, 0.f, 0.f, 0.f);
}

__global__ void k_hist(const int* __restrict__ dst, int* __restrict__ cnt) {
    int e = blockIdx.x * 256 + threadIdx.x;
    if (e < NE) atomicAdd(&cnt[dst[e]], 1);
}

__global__ void k_dinv(const int* __restrict__ cnt, float* __restrict__ dinv) {
    int i = blockIdx.x * 256 + threadIdx.x;
    if (i < NN) dinv[i] = rsqrtf((float)(cnt[i] + 1));   // +1 self-loop
}

__global__ __launch_bounds__(256) void k_scan1(const int* __restrict__ cnt,
                                               int* __restrict__ incl,
                                               int* __restrict__ bsums) {
    __shared__ int sh[256];
    int i = blockIdx.x * 256 + threadIdx.x;
    int v = (i < NN) ? cnt[i] : 0;
    sh[threadIdx.x] = v;
    __syncthreads();
    for (int d = 1; d < 256; d <<= 1) {
        int t = (threadIdx.x >= d) ? sh[threadIdx.x - d] : 0;
        __syncthreads();
        sh[threadIdx.x] += t;
        __syncthreads();
    }
    incl[i] = sh[threadIdx.x];
    if (threadIdx.x == 255) bsums[blockIdx.x] = sh[255];
}

__global__ __launch_bounds__(256) void k_scan2(int* __restrict__ bsums) {
    __shared__ int sh[256];
    int v = (threadIdx.x < 196) ? bsums[threadIdx.x] : 0;
    sh[threadIdx.x] = v;
    __syncthreads();
    for (int d = 1; d < 256; d <<= 1) {
        int t = (threadIdx.x >= d) ? sh[threadIdx.x - d] : 0;
        __syncthreads();
        sh[threadIdx.x] += t;
        __syncthreads();
    }
    if (threadIdx.x < 196) bsums[threadIdx.x] = sh[threadIdx.x] - v;  // exclusive
}

__global__ void k_scan3(const int* __restrict__ cnt, int* __restrict__ incl_cursor,
                        const int* __restrict__ bsums, int* __restrict__ offs) {
    int i = blockIdx.x * 256 + threadIdx.x;
    if (i >= NN) return;
    int excl = incl_cursor[i] - cnt[i] + bsums[blockIdx.x];
    offs[i] = excl;
    incl_cursor[i] = excl;   // becomes the fill cursor
    if (i == NN - 1) offs[NN] = NE;
}

__global__ void k_fill(const int* __restrict__ src, const int* __restrict__ dst,
                       int* __restrict__ cursor, int* __restrict__ csr_src) {
    int e = blockIdx.x * 256 + threadIdx.x;
    if (e < NE) {
        int p = atomicAdd(&cursor[dst[e]], 1);
        csr_src[p] = src[e];
    }
}

__global__ void k_feat(const float* __restrict__ w, const float* __restrict__ lw,
                       const float* __restrict__ lb, float* __restrict__ A,
                       ushort* __restrict__ Ab) {
    int i = blockIdx.x * 256 + threadIdx.x;
    if (i < NN * DIM) {
        int n = i >> 7, d = i & 127;
        float v = w[n] * lw[d] + lb[d];
        A[i] = v;
        Ab[i] = f2b(v);
    }
}

// Wave-per-node gather, bf16 neighbor rows (256 B/edge). Lane owns dims
// {2*lane, 2*lane+1}. Qb[n] = bf16( -( sum w_e*Xb[src] + X[n]/deg ) )
__global__ __launch_bounds__(256) void k_gather1(
        const ushort* __restrict__ Xb, const float* __restrict__ X,
        const int* __restrict__ offs, const int* __restrict__ csr_src,
        const float* __restrict__ dinv, ushort* __restrict__ Qb) {
    int n = blockIdx.x * 4 + (threadIdx.x >> 6);
    int lane = threadIdx.x & 63;
    int j0 = offs[n], j1 = offs[n + 1];
    float dn = dinv[n];
    float a0 = 0.f, a1 = 0.f;
    const uint* Xu = (const uint*)Xb;
    for (int base = j0; base < j1; base += 64) {
        int m = j1 - base; if (m > 64) m = 64;
        int s = 0; float wv = 0.f;
        if (lane < m) { s = csr_src[base + lane]; wv = dinv[s] * dn; }
        int t = 0;
        for (; t + 4 <= m; t += 4) {
            int s0 = __shfl(s, t, 64),     s1 = __shfl(s, t + 1, 64);
            int s2 = __shfl(s, t + 2, 64), s3 = __shfl(s, t + 3, 64);
            float w0 = __shfl(wv, t, 64),     w1 = __shfl(wv, t + 1, 64);
            float w2 = __shfl(wv, t + 2, 64), w3 = __shfl(wv, t + 3, 64);
            uint u0 = Xu[(size_t)s0 * 64 + lane];
            uint u1 = Xu[(size_t)s1 * 64 + lane];
            uint u2 = Xu[(size_t)s2 * 64 + lane];
            uint u3 = Xu[(size_t)s3 * 64 + lane];
            a0 = fmaf(w0, __uint_as_float(u0 << 16), a0);
            a1 = fmaf(w0, __uint_as_float(u0 & 0xFFFF0000u), a1);
            a0 = fmaf(w1, __uint_as_float(u1 << 16), a0);
            a1 = fmaf(w1, __uint_as_float(u1 & 0xFFFF0000u), a1);
            a0 = fmaf(w2, __uint_as_float(u2 << 16), a0);
            a1 = fmaf(w2, __uint_as_float(u2 & 0xFFFF0000u), a1);
            a0 = fmaf(w3, __uint_as_float(u3 << 16), a0);
            a1 = fmaf(w3, __uint_as_float(u3 & 0xFFFF0000u), a1);
        }
        for (; t < m; ++t) {
            int ss = __shfl(s, t, 64);
            float ww = __shfl(wv, t, 64);
            uint u = Xu[(size_t)ss * 64 + lane];
            a0 = fmaf(ww, __uint_as_float(u << 16), a0);
            a1 = fmaf(ww, __uint_as_float(u & 0xFFFF0000u), a1);
        }
    }
    float id = dn * dn;
    float2 xn = ((const float2*)(X + (size_t)n * DIM))[lane];
    float q0 = -(a0 + xn.x * id);
    float q1 = -(a1 + xn.y * id);
    ushort2 ub; ub.x = f2b(q0); ub.y = f2b(q1);
    ((ushort2*)(Qb + (size_t)n * DIM))[lane] = ub;
}

// R[n] = -2*( sum w_e*X1b[src] + X1b[n]/deg ) - X0[n]   (R fp32)
__global__ __launch_bounds__(256) void k_gather2(
        const ushort* __restrict__ X1b, const float* __restrict__ X0,
        const int* __restrict__ offs, const int* __restrict__ csr_src,
        const float* __restrict__ dinv, float* __restrict__ R) {
    int n = blockIdx.x * 4 + (threadIdx.x >> 6);
    int lane = threadIdx.x & 63;
    int j0 = offs[n], j1 = offs[n + 1];
    float dn = dinv[n];
    float a0 = 0.f, a1 = 0.f;
    const uint* Xu = (const uint*)X1b;
    for (int base = j0; base < j1; base += 64) {
        int m = j1 - base; if (m > 64) m = 64;
        int s = 0; float wv = 0.f;
        if (lane < m) { s = csr_src[base + lane]; wv = dinv[s] * dn; }
        int t = 0;
        for (; t + 4 <= m; t += 4) {
            int s0 = __shfl(s, t, 64),     s1 = __shfl(s, t + 1, 64);
            int s2 = __shfl(s, t + 2, 64), s3 = __shfl(s, t + 3, 64);
            float w0 = __shfl(wv, t, 64),     w1 = __shfl(wv, t + 1, 64);
            float w2 = __shfl(wv, t + 2, 64), w3 = __shfl(wv, t + 3, 64);
            uint u0 = Xu[(size_t)s0 * 64 + lane];
            uint u1 = Xu[(size_t)s1 * 64 + lane];
            uint u2 = Xu[(size_t)s2 * 64 + lane];
            uint u3 = Xu[(size_t)s3 * 64 + lane];
            a0 = fmaf(w0, __uint_as_float(u0 << 16), a0);
            a1 = fmaf(w0, __uint_as_float(u0 & 0xFFFF0000u), a1);
            a0 = fmaf(w1, __uint_as_float(u1 << 16), a0);
            a1 = fmaf(w1, __uint_as_float(u1 & 0xFFFF0000u), a1);
            a0 = fmaf(w2, __uint_as_float(u2 << 16), a0);
            a1 = fmaf(w2, __uint_as_float(u2 & 0xFFFF0000u), a1);
            a0 = fmaf(w3, __uint_as_float(u3 << 16), a0);
            a1 = fmaf(w3, __uint_as_float(u3 & 0xFFFF0000u), a1);
        }
        for (; t < m; ++t) {
            int ss = __shfl(s, t, 64);
            float ww = __shfl(wv, t, 64);
            uint u = Xu[(size_t)ss * 64 + lane];
            a0 = fmaf(ww, __uint_as_float(u << 16), a0);
            a1 = fmaf(ww, __uint_as_float(u & 0xFFFF0000u), a1);
        }
    }
    float id = dn * dn;
    uint us = ((const uint*)X1b)[(size_t)n * 64 + lane];
    float x1a = __uint_as_float(us << 16), x1b = __uint_as_float(us & 0xFFFF0000u);
    float2 x0 = ((const float2*)(X0 + (size_t)n * DIM))[lane];
    float2 r;
    r.x = -2.f * (a0 + x1a * id) - x0.x;
    r.y = -2.f * (a1 + x1b * id) - x0.y;
    ((float2*)(R + (size_t)n * DIM))[lane] = r;
}

// out = relu([X0|X1|X2] @ W + bias). 128 nodes x 128 cols / block, K-chunk 32,
// per-thread 8x8 tile (64 B LDS per 64 lane-FMAs = LDS-balanced), all LDS
// access patterns <=2-way bank aliasing. X1 operand arrives as bf16 (X1b),
// expanded to fp32 during LDS staging. Writes fp32 out + bf16 outb.
// out may alias X0: each block touches only its own 128 rows, writes last.
__global__ __launch_bounds__(256) void k_gemm(
        const float* __restrict__ X0, const ushort* __restrict__ X1b,
        const float* __restrict__ X2, const float* __restrict__ W,
        const float* __restrict__ bias, float* __restrict__ out,
        ushort* __restrict__ outb) {
    __shared__ float As[32 * 128];   // [k][node] 16 KB
    __shared__ float Ws[32 * 128];   // [k][col]  16 KB
    int tid = threadIdx.x;
    int nbase = blockIdx.x * 128;
    int wv = tid >> 6, l = tid & 63;
    int ng = (l & 7) | ((wv & 1) << 3);          // node group (8 nodes)
    int jg = ((l >> 3) & 7) | (((wv >> 1) & 1) << 3);  // col group (8 cols)
    int n_a = tid >> 1;       // staging node 0..127
    int half = tid & 1;       // 16-float half of the 32-float k-window
    int n_ld = nbase + n_a; if (n_ld >= NN) n_ld = NN - 1;

    float4 acc[8][2];
#pragma unroll
    for (int r = 0; r < 8; ++r) { acc[r][0] = make_float4(0,0,0,0); acc[r][1] = make_float4(0,0,0,0); }

    const float4* W4 = (const float4*)W;
    const float4* Ws4 = (const float4*)Ws;
    const float4* As4 = (const float4*)As;

    float4 caf[4]; uint4 cau; uint4 cau2; float4 cw[4];
    float4 naf[4]; uint4 nau; uint4 nau2; float4 nw[4];
    {   // prefetch chunk 0 (part 0 = X0, fp32)
        const float4* xr = (const float4*)(X0 + (size_t)n_ld * DIM) + half * 4;
        caf[0] = xr[0]; caf[1] = xr[1]; caf[2] = xr[2]; caf[3] = xr[3];
        cw[0] = W4[tid]; cw[1] = W4[tid + 256]; cw[2] = W4[tid + 512]; cw[3] = W4[tid + 768];
    }
    for (int c = 0; c < 12; ++c) {
        int part = c >> 2;
        __syncthreads();
        if (part == 1) {   // expand bf16 staging regs into As
            uint uu[8] = {cau.x, cau.y, cau.z, cau.w, cau2.x, cau2.y, cau2.z, cau2.w};
#pragma unroll
            for (int q = 0; q < 8; ++q) {
                int kl = half * 16 + q * 2;
                As[(kl + 0) * 128 + n_a] = __uint_as_float(uu[q] << 16);
                As[(kl + 1) * 128 + n_a] = __uint_as_float(uu[q] & 0xFFFF0000u);
            }
        } else {
#pragma unroll
            for (int i = 0; i < 4; ++i) {
                int kl = half * 16 + i * 4;
                As[(kl + 0) * 128 + n_a] = caf[i].x;
                As[(kl + 1) * 128 + n_a] = caf[i].y;
                As[(kl + 2) * 128 + n_a] = caf[i].z;
                As[(kl + 3) * 128 + n_a] = caf[i].w;
            }
        }
        ((float4*)Ws)[tid]       = cw[0];
        ((float4*)Ws)[tid + 256] = cw[1];
        ((float4*)Ws)[tid + 512] = cw[2];
        ((float4*)Ws)[tid + 768] = cw[3];
        __syncthreads();
        if (c + 1 < 12) {   // prefetch next chunk
            int p2 = (c + 1) >> 2;
            int k0 = ((c + 1) & 3) * 32;
            if (p2 == 1) {
                const uint4* xr = (const uint4*)(X1b + (size_t)n_ld * DIM + k0) + half * 2;
                nau = xr[0]; nau2 = xr[1];
            } else {
                const float* Xp = (p2 == 0) ? X0 : X2;
                const float4* xr = (const float4*)(Xp + (size_t)n_ld * DIM + k0) + half * 4;
                naf[0] = xr[0]; naf[1] = xr[1]; naf[2] = xr[2]; naf[3] = xr[3];
            }
            const float4* ws2 = W4 + (size_t)(c + 1) * 1024;
            nw[0] = ws2[tid]; nw[1] = ws2[tid + 256]; nw[2] = ws2[tid + 512]; nw[3] = ws2[tid + 768];
        }
#pragma unroll 4
        for (int k = 0; k < 32; ++k) {
            float4 w0 = Ws4[k * 32 + jg * 2];
            float4 w1 = Ws4[k * 32 + jg * 2 + 1];
            float4 aA = As4[k * 32 + ng * 2];
            float4 aB = As4[k * 32 + ng * 2 + 1];
            float av[8] = {aA.x, aA.y, aA.z, aA.w, aB.x, aB.y, aB.z, aB.w};
#pragma unroll
            for (int r = 0; r < 8; ++r) {
                acc[r][0].x = fmaf(av[r], w0.x, acc[r][0].x);
                acc[r][0].y = fmaf(av[r], w0.y, acc[r][0].y);
                acc[r][0].z = fmaf(av[r], w0.z, acc[r][0].z);
                acc[r][0].w = fmaf(av[r], w0.w, acc[r][0].w);
                acc[r][1].x = fmaf(av[r], w1.x, acc[r][1].x);
                acc[r][1].y = fmaf(av[r], w1.y, acc[r][1].y);
                acc[r][1].z = fmaf(av[r], w1.z, acc[r][1].z);
                acc[r][1].w = fmaf(av[r], w1.w, acc[r][1].w);
            }
        }
#pragma unroll
        for (int i = 0; i < 4; ++i) { caf[i] = naf[i]; cw[i] = nw[i]; }
        cau = nau; cau2 = nau2;
    }

    const float4* bias4 = (const float4*)bias;
    float4 b0 = bias4[jg * 2], b1 = bias4[jg * 2 + 1];
#pragma unroll
    for (int r = 0; r < 8; ++r) {
        int node = nbase + ng * 8 + r;
        if (node < NN) {
            float4 o0, o1;
            o0.x = fmaxf(acc[r][0].x + b0.x, 0.f);
            o0.y = fmaxf(acc[r][0].y + b0.y, 0.f);
            o0.z = fmaxf(acc[r][0].z + b0.z, 0.f);
            o0.w = fmaxf(acc[r][0].w + b0.w, 0.f);
            o1.x = fmaxf(acc[r][1].x + b1.x, 0.f);
            o1.y = fmaxf(acc[r][1].y + b1.y, 0.f);
            o1.z = fmaxf(acc[r][1].z + b1.z, 0.f);
            o1.w = fmaxf(acc[r][1].w + b1.w, 0.f);
            float4* op = (float4*)(out + (size_t)node * DIM + jg * 8);
            op[0] = o0; op[1] = o1;
            uint4 ub;
            ub.x = (uint)f2b(o0.x) | ((uint)f2b(o0.y) << 16);
            ub.y = (uint)f2b(o0.z) | ((uint)f2b(o0.w) << 16);
            ub.z = (uint)f2b(o1.x) | ((uint)f2b(o1.y) << 16);
            ub.w = (uint)f2b(o1.z) | ((uint)f2b(o1.w) << 16);
            *(uint4*)(outb + (size_t)node * DIM + jg * 8) = ub;
        }
    }
}

// logits[n] = emb[n] . pred_w + pred_b ; one 64-lane wave per node
__global__ void k_predict(const float* __restrict__ emb, const float* __restrict__ pw,
                          const float* __restrict__ pb, float* __restrict__ out) {
    int t = blockIdx.x * 256 + threadIdx.x;
    int n = t >> 6;
    if (n >= NN) return;
    int lane = t & 63;
    const float* row = emb + (size_t)n * DIM;
    float v = row[lane] * pw[lane] + row[lane + 64] * pw[lane + 64];
#pragma unroll
    for (int off = 32; off > 0; off >>= 1) v += __shfl_down(v, off, 64);
    if (lane == 0) out[n] = v + pb[0];
}

extern "C" void kernel_launch(void* const* d_in, const int* in_sizes, int n_in,
                              void* d_out, int out_size, void* d_ws, size_t ws_size,
                              hipStream_t stream) {
    int i_weights = 0, i_src = 1, i_dst = 2, i_lw = 3, i_lb = 4,
        i_cw = 5, i_cb = 6, i_pw = 7, i_pb = 8;
    {
        int seen600k = 0, seen128 = 0;
        for (int i = 0; i < n_in; ++i) {
            int s = in_sizes[i];
            if (s == 50000) i_weights = i;
            else if (s == 600000) { if (seen600k == 0) i_src = i; else i_dst = i; ++seen600k; }
            else if (s == 128) { if (seen128 == 0) i_lw = i; else if (seen128 == 1) i_lb = i; else i_pw = i; ++seen128; }
            else if (s == 147456) i_cw = i;
            else if (s == 384) i_cb = i;
            else if (s == 1) i_pb = i;
        }
    }
    const float* weights = (const float*)d_in[i_weights];
    const int*   src     = (const int*)d_in[i_src];
    const int*   dst     = (const int*)d_in[i_dst];
    const float* lin_w   = (const float*)d_in[i_lw];
    const float* lin_b   = (const float*)d_in[i_lb];
    const float* cheb_w  = (const float*)d_in[i_cw];
    const float* cheb_b  = (const float*)d_in[i_cb];
    const float* pred_w  = (const float*)d_in[i_pw];
    const float* pred_b  = (const float*)d_in[i_pb];
    float* out = (float*)d_out;

    // Workspace (79.6 MB, same as passing rounds):
    float* ws      = (float*)d_ws;
    float* dinv    = ws;                           // 50048 floats
    int*   offs    = (int*)(ws + 50048);           // 50056 ints
    int*   csr_src = offs + 50056;                 // 600000 ints
    float* P       = (float*)(csr_src + 600000);   // 6.4M floats (fp32 layer state)
    float* R       = P + (size_t)NN * DIM;         // 6.4M floats (X2)
    ushort* Qb     = (ushort*)(R + (size_t)NN * DIM);  // 6.4M bf16 (X1)
    ushort* Pb     = Qb + (size_t)NN * DIM;        // 6.4M bf16 (shadow of P)
    int* cnt   = (int*)P;          // scan temporaries alias P (pre-k_feat)
    int* incl  = cnt + 50176;
    int* bsums = incl + 50176;

    // --- CSR build (once) ---
    k_zero<<<49, 256, 0, stream>>>((float*)cnt, 12544);
    k_hist<<<2344, 256, 0, stream>>>(dst, cnt);
    k_dinv<<<196, 256, 0, stream>>>(cnt, dinv);
    k_scan1<<<196, 256, 0, stream>>>(cnt, incl, bsums);
    k_scan2<<<1, 256, 0, stream>>>(bsums);
    k_scan3<<<196, 256, 0, stream>>>(cnt, incl, bsums, offs);
    k_fill<<<2344, 256, 0, stream>>>(src, dst, incl, csr_src);

    // --- network ---
    k_feat<<<25000, 256, 0, stream>>>(weights, lin_w, lin_b, P, Pb);
    for (int l = 0; l < 3; ++l) {
        k_gather1<<<12500, 256, 0, stream>>>(Pb, P, offs, csr_src, dinv, Qb);
        k_gather2<<<12500, 256, 0, stream>>>(Qb, P, offs, csr_src, dinv, R);
        k_gemm<<<391, 256, 0, stream>>>(P, Qb, R, cheb_w + (size_t)l * KD * DIM,
                                        cheb_b + (size_t)l * DIM, P, Pb);
    }
    k_predict<<<12500, 256, 0, stream>>>(P, pred_w, pred_b, out);
}

// Round 8
// 441.007 us; speedup vs baseline: 15.2891x; 1.5758x over previous
//
#include <hip/hip_runtime.h>

typedef unsigned int uint;
typedef unsigned short ushort;

#define NN 50000
#define NE 600000
#define DIM 128
#define KD 384   // K*DIM
#define PADK 40  // LDS row stride (ushorts) for MFMA tiles

typedef __attribute__((ext_vector_type(8))) short short8;
typedef __attribute__((ext_vector_type(4))) float float4v;

static __device__ __forceinline__ ushort f2b(float f) {   // fp32 -> bf16 RNE
    uint u = __float_as_uint(f);
    return (ushort)((u + 0x7FFFu + ((u >> 16) & 1u)) >> 16);
}

__global__ void k_zero(float* __restrict__ p, int n4) {
    int i = blockIdx.x * 256 + threadIdx.x;
    if (i < n4) ((float4*)p)[i] = make_float4(0.f, 0.f, 0.f, 0.f);
}

__global__ void k_hist(const int* __restrict__ dst, int* __restrict__ cnt) {
    int e = blockIdx.x * 256 + threadIdx.x;
    if (e < NE) atomicAdd(&cnt[dst[e]], 1);
}

__global__ void k_dinv(const int* __restrict__ cnt, float* __restrict__ dinv) {
    int i = blockIdx.x * 256 + threadIdx.x;
    if (i < NN) dinv[i] = rsqrtf((float)(cnt[i] + 1));   // +1 self-loop
}

__global__ __launch_bounds__(256) void k_scan1(const int* __restrict__ cnt,
                                               int* __restrict__ incl,
                                               int* __restrict__ bsums) {
    __shared__ int sh[256];
    int i = blockIdx.x * 256 + threadIdx.x;
    int v = (i < NN) ? cnt[i] : 0;
    sh[threadIdx.x] = v;
    __syncthreads();
    for (int d = 1; d < 256; d <<= 1) {
        int t = (threadIdx.x >= d) ? sh[threadIdx.x - d] : 0;
        __syncthreads();
        sh[threadIdx.x] += t;
        __syncthreads();
    }
    incl[i] = sh[threadIdx.x];
    if (threadIdx.x == 255) bsums[blockIdx.x] = sh[255];
}

__global__ __launch_bounds__(256) void k_scan2(int* __restrict__ bsums) {
    __shared__ int sh[256];
    int v = (threadIdx.x < 196) ? bsums[threadIdx.x] : 0;
    sh[threadIdx.x] = v;
    __syncthreads();
    for (int d = 1; d < 256; d <<= 1) {
        int t = (threadIdx.x >= d) ? sh[threadIdx.x - d] : 0;
        __syncthreads();
        sh[threadIdx.x] += t;
        __syncthreads();
    }
    if (threadIdx.x < 196) bsums[threadIdx.x] = sh[threadIdx.x] - v;  // exclusive
}

__global__ void k_scan3(const int* __restrict__ cnt, int* __restrict__ incl_cursor,
                        const int* __restrict__ bsums, int* __restrict__ offs) {
    int i = blockIdx.x * 256 + threadIdx.x;
    if (i >= NN) return;
    int excl = incl_cursor[i] - cnt[i] + bsums[blockIdx.x];
    offs[i] = excl;
    incl_cursor[i] = excl;   // becomes the fill cursor
    if (i == NN - 1) offs[NN] = NE;
}

__global__ void k_fill(const int* __restrict__ src, const int* __restrict__ dst,
                       int* __restrict__ cursor, int* __restrict__ csr_src) {
    int e = blockIdx.x * 256 + threadIdx.x;
    if (e < NE) {
        int p = atomicAdd(&cursor[dst[e]], 1);
        csr_src[p] = src[e];
    }
}

// cheb_w [3][K=384][N=128] fp32 -> Wt [3][N=128][K=384] bf16
__global__ void k_wt(const float* __restrict__ cw, ushort* __restrict__ wt) {
    int i = blockIdx.x * 256 + threadIdx.x;
    if (i < 3 * KD * DIM) {
        int l = i / (KD * DIM), rem = i - l * (KD * DIM);
        int k = rem >> 7, n = rem & 127;
        wt[(size_t)l * KD * DIM + (size_t)n * KD + k] = f2b(cw[i]);
    }
}

__global__ void k_feat(const float* __restrict__ w, const float* __restrict__ lw,
                       const float* __restrict__ lb, float* __restrict__ A,
                       ushort* __restrict__ Ab) {
    int i = blockIdx.x * 256 + threadIdx.x;
    if (i < NN * DIM) {
        int n = i >> 7, d = i & 127;
        float v = w[n] * lw[d] + lb[d];
        A[i] = v;
        Ab[i] = f2b(v);
    }
}

// Wave-per-node gather, bf16 neighbor rows. Lane owns dims {2*lane, 2*lane+1}.
// Qb[n] = bf16( -( sum w_e*Xb[src] + X[n]/deg ) )
__global__ __launch_bounds__(256) void k_gather1(
        const ushort* __restrict__ Xb, const float* __restrict__ X,
        const int* __restrict__ offs, const int* __restrict__ csr_src,
        const float* __restrict__ dinv, ushort* __restrict__ Qb) {
    int n = blockIdx.x * 4 + (threadIdx.x >> 6);
    int lane = threadIdx.x & 63;
    int j0 = offs[n], j1 = offs[n + 1];
    float dn = dinv[n];
    float a0 = 0.f, a1 = 0.f;
    const uint* Xu = (const uint*)Xb;
    for (int base = j0; base < j1; base += 64) {
        int m = j1 - base; if (m > 64) m = 64;
        int s = 0; float wv = 0.f;
        if (lane < m) { s = csr_src[base + lane]; wv = dinv[s] * dn; }
        int t = 0;
        for (; t + 4 <= m; t += 4) {
            int s0 = __shfl(s, t, 64),     s1 = __shfl(s, t + 1, 64);
            int s2 = __shfl(s, t + 2, 64), s3 = __shfl(s, t + 3, 64);
            float w0 = __shfl(wv, t, 64),     w1 = __shfl(wv, t + 1, 64);
            float w2 = __shfl(wv, t + 2, 64), w3 = __shfl(wv, t + 3, 64);
            uint u0 = Xu[(size_t)s0 * 64 + lane];
            uint u1 = Xu[(size_t)s1 * 64 + lane];
            uint u2 = Xu[(size_t)s2 * 64 + lane];
            uint u3 = Xu[(size_t)s3 * 64 + lane];
            a0 = fmaf(w0, __uint_as_float(u0 << 16), a0);
            a1 = fmaf(w0, __uint_as_float(u0 & 0xFFFF0000u), a1);
            a0 = fmaf(w1, __uint_as_float(u1 << 16), a0);
            a1 = fmaf(w1, __uint_as_float(u1 & 0xFFFF0000u), a1);
            a0 = fmaf(w2, __uint_as_float(u2 << 16), a0);
            a1 = fmaf(w2, __uint_as_float(u2 & 0xFFFF0000u), a1);
            a0 = fmaf(w3, __uint_as_float(u3 << 16), a0);
            a1 = fmaf(w3, __uint_as_float(u3 & 0xFFFF0000u), a1);
        }
        for (; t < m; ++t) {
            int ss = __shfl(s, t, 64);
            float ww = __shfl(wv, t, 64);
            uint u = Xu[(size_t)ss * 64 + lane];
            a0 = fmaf(ww, __uint_as_float(u << 16), a0);
            a1 = fmaf(ww, __uint_as_float(u & 0xFFFF0000u), a1);
        }
    }
    float id = dn * dn;
    float2 xn = ((const float2*)(X + (size_t)n * DIM))[lane];
    ushort2 ub; ub.x = f2b(-(a0 + xn.x * id)); ub.y = f2b(-(a1 + xn.y * id));
    ((ushort2*)(Qb + (size_t)n * DIM))[lane] = ub;
}

// Rb[n] = bf16( -2*( sum w_e*X1b[src] + X1b[n]/deg ) - X0[n] )
__global__ __launch_bounds__(256) void k_gather2(
        const ushort* __restrict__ X1b, const float* __restrict__ X0,
        const int* __restrict__ offs, const int* __restrict__ csr_src,
        const float* __restrict__ dinv, ushort* __restrict__ Rb) {
    int n = blockIdx.x * 4 + (threadIdx.x >> 6);
    int lane = threadIdx.x & 63;
    int j0 = offs[n], j1 = offs[n + 1];
    float dn = dinv[n];
    float a0 = 0.f, a1 = 0.f;
    const uint* Xu = (const uint*)X1b;
    for (int base = j0; base < j1; base += 64) {
        int m = j1 - base; if (m > 64) m = 64;
        int s = 0; float wv = 0.f;
        if (lane < m) { s = csr_src[base + lane]; wv = dinv[s] * dn; }
        int t = 0;
        for (; t + 4 <= m; t += 4) {
            int s0 = __shfl(s, t, 64),     s1 = __shfl(s, t + 1, 64);
            int s2 = __shfl(s, t + 2, 64), s3 = __shfl(s, t + 3, 64);
            float w0 = __shfl(wv, t, 64),     w1 = __shfl(wv, t + 1, 64);
            float w2 = __shfl(wv, t + 2, 64), w3 = __shfl(wv, t + 3, 64);
            uint u0 = Xu[(size_t)s0 * 64 + lane];
            uint u1 = Xu[(size_t)s1 * 64 + lane];
            uint u2 = Xu[(size_t)s2 * 64 + lane];
            uint u3 = Xu[(size_t)s3 * 64 + lane];
            a0 = fmaf(w0, __uint_as_float(u0 << 16), a0);
            a1 = fmaf(w0, __uint_as_float(u0 & 0xFFFF0000u), a1);
            a0 = fmaf(w1, __uint_as_float(u1 << 16), a0);
            a1 = fmaf(w1, __uint_as_float(u1 & 0xFFFF0000u), a1);
            a0 = fmaf(w2, __uint_as_float(u2 << 16), a0);
            a1 = fmaf(w2, __uint_as_float(u2 & 0xFFFF0000u), a1);
            a0 = fmaf(w3, __uint_as_float(u3 << 16), a0);
            a1 = fmaf(w3, __uint_as_float(u3 & 0xFFFF0000u), a1);
        }
        for (; t < m; ++t) {
            int ss = __shfl(s, t, 64);
            float ww = __shfl(wv, t, 64);
            uint u = Xu[(size_t)ss * 64 + lane];
            a0 = fmaf(ww, __uint_as_float(u << 16), a0);
            a1 = fmaf(ww, __uint_as_float(u & 0xFFFF0000u), a1);
        }
    }
    float id = dn * dn;
    uint us = ((const uint*)X1b)[(size_t)n * 64 + lane];
    float x1a = __uint_as_float(us << 16), x1b = __uint_as_float(us & 0xFFFF0000u);
    float2 x0 = ((const float2*)(X0 + (size_t)n * DIM))[lane];
    ushort2 ub;
    ub.x = f2b(-2.f * (a0 + x1a * id) - x0.x);
    ub.y = f2b(-2.f * (a1 + x1b * id) - x0.y);
    ((ushort2*)(Rb + (size_t)n * DIM))[lane] = ub;
}

// MFMA GEMM: out = relu([X0|X1|X2] @ W + bias), all operands bf16, fp32 acc.
// 128 nodes x 128 cols per block, 4 waves, each wave owns a 64x64 quadrant
// as 4x4 tiles of 16x16x32 bf16 MFMA. Wt is pre-transposed [n][k] bf16, so
// A and B frags are both k-contiguous 16B LDS reads. K-chunks of 32 (12 total).
// Writes fp32 out (P) + bf16 outb (Pb). Block reads only its own 128 rows of
// X0b (=outb), all reads precede writes -> aliasing safe.
__global__ __launch_bounds__(256) void k_gemm(
        const ushort* __restrict__ X0b, const ushort* __restrict__ X1b,
        const ushort* __restrict__ X2b, const ushort* __restrict__ Wt,
        const float* __restrict__ bias, float* __restrict__ out,
        ushort* __restrict__ outb) {
    __shared__ ushort As[128 * PADK];   // [m][k] stride 40, 10 KB
    __shared__ ushort Bs[128 * PADK];   // [n][k] stride 40, 10 KB
    int tid = threadIdx.x;
    int nbase = blockIdx.x * 128;
    int wave = tid >> 6, lane = tid & 63;
    int wr = wave >> 1, wc = wave & 1;      // 64x64 quadrant
    int l15 = lane & 15, quad = lane >> 4;

    float4v acc[4][4];
#pragma unroll
    for (int i = 0; i < 4; ++i)
#pragma unroll
        for (int j = 0; j < 4; ++j) acc[i][j] = (float4v)0.f;

    int srow = tid >> 1, shalf = tid & 1;   // staging: row 0..127, 32B half
    int gm = nbase + srow; if (gm >= NN) gm = NN - 1;

    for (int c = 0; c < 12; ++c) {
        int part = c >> 2;
        int k0 = (c & 3) * 32;
        const ushort* Xp = (part == 0) ? X0b : ((part == 1) ? X1b : X2b);
        const uint4* ga = (const uint4*)(Xp + (size_t)gm * DIM + k0 + shalf * 16);
        uint4 a0 = ga[0], a1 = ga[1];
        const uint4* gb = (const uint4*)(Wt + (size_t)srow * KD + c * 32 + shalf * 16);
        uint4 b0 = gb[0], b1 = gb[1];
        __syncthreads();   // previous chunk's LDS readers done
        uint4* pa = (uint4*)(As + srow * PADK + shalf * 16);
        pa[0] = a0; pa[1] = a1;
        uint4* pb = (uint4*)(Bs + srow * PADK + shalf * 16);
        pb[0] = b0; pb[1] = b1;
        __syncthreads();
        short8 af[4], bf[4];
#pragma unroll
        for (int i = 0; i < 4; ++i) {
            af[i] = *(const short8*)(As + (wr * 64 + i * 16 + l15) * PADK + quad * 8);
            bf[i] = *(const short8*)(Bs + (wc * 64 + i * 16 + l15) * PADK + quad * 8);
        }
#pragma unroll
        for (int i = 0; i < 4; ++i)
#pragma unroll
            for (int j = 0; j < 4; ++j)
                acc[i][j] = __builtin_amdgcn_mfma_f32_16x16x32_bf16(
                    af[i], bf[j], acc[i][j], 0, 0, 0);
    }

    float bv[4];
#pragma unroll
    for (int j = 0; j < 4; ++j) bv[j] = bias[wc * 64 + j * 16 + l15];
#pragma unroll
    for (int i = 0; i < 4; ++i) {
#pragma unroll
        for (int r = 0; r < 4; ++r) {
            int node = nbase + wr * 64 + i * 16 + quad * 4 + r;
            if (node < NN) {
#pragma unroll
                for (int j = 0; j < 4; ++j) {
                    int col = wc * 64 + j * 16 + l15;
                    float v = fmaxf(acc[i][j][r] + bv[j], 0.f);
                    out[(size_t)node * DIM + col] = v;
                    outb[(size_t)node * DIM + col] = f2b(v);
                }
            }
        }
    }
}

// logits[n] = emb[n] . pred_w + pred_b ; one 64-lane wave per node
__global__ void k_predict(const float* __restrict__ emb, const float* __restrict__ pw,
                          const float* __restrict__ pb, float* __restrict__ out) {
    int t = blockIdx.x * 256 + threadIdx.x;
    int n = t >> 6;
    if (n >= NN) return;
    int lane = t & 63;
    const float* row = emb + (size_t)n * DIM;
    float v = row[lane] * pw[lane] + row[lane + 64] * pw[lane + 64];
#pragma unroll
    for (int off = 32; off > 0; off >>= 1) v += __shfl_down(v, off, 64);
    if (lane == 0) out[n] = v + pb[0];
}

extern "C" void kernel_launch(void* const* d_in, const int* in_sizes, int n_in,
                              void* d_out, int out_size, void* d_ws, size_t ws_size,
                              hipStream_t stream) {
    int i_weights = 0, i_src = 1, i_dst = 2, i_lw = 3, i_lb = 4,
        i_cw = 5, i_cb = 6, i_pw = 7, i_pb = 8;
    {
        int seen600k = 0, seen128 = 0;
        for (int i = 0; i < n_in; ++i) {
            int s = in_sizes[i];
            if (s == 50000) i_weights = i;
            else if (s == 600000) { if (seen600k == 0) i_src = i; else i_dst = i; ++seen600k; }
            else if (s == 128) { if (seen128 == 0) i_lw = i; else if (seen128 == 1) i_lb = i; else i_pw = i; ++seen128; }
            else if (s == 147456) i_cw = i;
            else if (s == 384) i_cb = i;
            else if (s == 1) i_pb = i;
        }
    }
    const float* weights = (const float*)d_in[i_weights];
    const int*   src     = (const int*)d_in[i_src];
    const int*   dst     = (const int*)d_in[i_dst];
    const float* lin_w   = (const float*)d_in[i_lw];
    const float* lin_b   = (const float*)d_in[i_lb];
    const float* cheb_w  = (const float*)d_in[i_cw];
    const float* cheb_b  = (const float*)d_in[i_cb];
    const float* pred_w  = (const float*)d_in[i_pw];
    const float* pred_b  = (const float*)d_in[i_pb];
    float* out = (float*)d_out;

    // Workspace (~67 MB):
    float* ws      = (float*)d_ws;
    float* dinv    = ws;                           // 50048 floats
    int*   offs    = (int*)(ws + 50048);           // 50056 ints
    int*   csr_src = offs + 50056;                 // 600000 ints
    float* P       = (float*)(csr_src + 600000);   // 6.4M floats (fp32 state)
    ushort* Pb     = (ushort*)(P + (size_t)NN * DIM);   // bf16 shadow of P
    ushort* Qb     = Pb + (size_t)NN * DIM;        // bf16 X1
    ushort* Rb     = Qb + (size_t)NN * DIM;        // bf16 X2
    ushort* Wtb    = Rb + (size_t)NN * DIM;        // 147456 bf16 (3x[128][384])
    int* cnt   = (int*)P;          // scan temporaries alias P (pre-k_feat)
    int* incl  = cnt + 50176;
    int* bsums = incl + 50176;

    // --- CSR build + weight transpose (once) ---
    k_zero<<<49, 256, 0, stream>>>((float*)cnt, 12544);
    k_hist<<<2344, 256, 0, stream>>>(dst, cnt);
    k_dinv<<<196, 256, 0, stream>>>(cnt, dinv);
    k_scan1<<<196, 256, 0, stream>>>(cnt, incl, bsums);
    k_scan2<<<1, 256, 0, stream>>>(bsums);
    k_scan3<<<196, 256, 0, stream>>>(cnt, incl, bsums, offs);
    k_fill<<<2344, 256, 0, stream>>>(src, dst, incl, csr_src);
    k_wt<<<576, 256, 0, stream>>>(cheb_w, Wtb);

    // --- network ---
    k_feat<<<25000, 256, 0, stream>>>(weights, lin_w, lin_b, P, Pb);
    for (int l = 0; l < 3; ++l) {
        k_gather1<<<12500, 256, 0, stream>>>(Pb, P, offs, csr_src, dinv, Qb);
        k_gather2<<<12500, 256, 0, stream>>>(Qb, P, offs, csr_src, dinv, Rb);
        k_gemm<<<391, 256, 0, stream>>>(Pb, Qb, Rb, Wtb + (size_t)l * KD * DIM,
                                        cheb_b + (size_t)l * DIM, P, Pb);
    }
    k_predict<<<12500, 256, 0, stream>>>(P, pred_w, pred_b, out);
}

// Round 9
// 388.327 us; speedup vs baseline: 17.3632x; 1.1357x over previous
//
#include <hip/hip_runtime.h>

typedef unsigned int uint;
typedef unsigned short ushort;

#define NN 50000
#define NE 600000
#define DIM 128
#define KD 384   // K*DIM
#define PADK 40  // LDS row stride (ushorts) for MFMA tiles

typedef __attribute__((ext_vector_type(8))) short short8;
typedef __attribute__((ext_vector_type(4))) float float4v;

static __device__ __forceinline__ ushort f2b(float f) {   // fp32 -> bf16 RNE
    uint u = __float_as_uint(f);
    return (ushort)((u + 0x7FFFu + ((u >> 16) & 1u)) >> 16);
}
static __device__ __forceinline__ float blo(uint u) { return __uint_as_float(u << 16); }
static __device__ __forceinline__ float bhi(uint u) { return __uint_as_float(u & 0xFFFF0000u); }

__global__ void k_zero(float* __restrict__ p, int n4) {
    int i = blockIdx.x * 256 + threadIdx.x;
    if (i < n4) ((float4*)p)[i] = make_float4(0.f, 0.f, 0.f, 0.f);
}

__global__ void k_hist(const int* __restrict__ dst, int* __restrict__ cnt) {
    int e = blockIdx.x * 256 + threadIdx.x;
    if (e < NE) atomicAdd(&cnt[dst[e]], 1);
}

__global__ void k_dinv(const int* __restrict__ cnt, float* __restrict__ dinv) {
    int i = blockIdx.x * 256 + threadIdx.x;
    if (i < NN) dinv[i] = rsqrtf((float)(cnt[i] + 1));   // +1 self-loop
}

__global__ __launch_bounds__(256) void k_scan1(const int* __restrict__ cnt,
                                               int* __restrict__ incl,
                                               int* __restrict__ bsums) {
    __shared__ int sh[256];
    int i = blockIdx.x * 256 + threadIdx.x;
    int v = (i < NN) ? cnt[i] : 0;
    sh[threadIdx.x] = v;
    __syncthreads();
    for (int d = 1; d < 256; d <<= 1) {
        int t = (threadIdx.x >= d) ? sh[threadIdx.x - d] : 0;
        __syncthreads();
        sh[threadIdx.x] += t;
        __syncthreads();
    }
    incl[i] = sh[threadIdx.x];
    if (threadIdx.x == 255) bsums[blockIdx.x] = sh[255];
}

__global__ __launch_bounds__(256) void k_scan2(int* __restrict__ bsums) {
    __shared__ int sh[256];
    int v = (threadIdx.x < 196) ? bsums[threadIdx.x] : 0;
    sh[threadIdx.x] = v;
    __syncthreads();
    for (int d = 1; d < 256; d <<= 1) {
        int t = (threadIdx.x >= d) ? sh[threadIdx.x - d] : 0;
        __syncthreads();
        sh[threadIdx.x] += t;
        __syncthreads();
    }
    if (threadIdx.x < 196) bsums[threadIdx.x] = sh[threadIdx.x] - v;  // exclusive
}

__global__ void k_scan3(const int* __restrict__ cnt, int* __restrict__ incl_cursor,
                        const int* __restrict__ bsums, int* __restrict__ offs) {
    int i = blockIdx.x * 256 + threadIdx.x;
    if (i >= NN) return;
    int excl = incl_cursor[i] - cnt[i] + bsums[blockIdx.x];
    offs[i] = excl;
    incl_cursor[i] = excl;   // becomes the fill cursor
    if (i == NN - 1) offs[NN] = NE;
}

__global__ void k_fill(const int* __restrict__ src, const int* __restrict__ dst,
                       int* __restrict__ cursor, int* __restrict__ csr_src) {
    int e = blockIdx.x * 256 + threadIdx.x;
    if (e < NE) {
        int p = atomicAdd(&cursor[dst[e]], 1);
        csr_src[p] = src[e];
    }
}

// cheb_w [3][K=384][N=128] fp32 -> Wt [3][N=128][K=384] bf16
__global__ void k_wt(const float* __restrict__ cw, ushort* __restrict__ wt) {
    int i = blockIdx.x * 256 + threadIdx.x;
    if (i < 3 * KD * DIM) {
        int l = i / (KD * DIM), rem = i - l * (KD * DIM);
        int k = rem >> 7, n = rem & 127;
        wt[(size_t)l * KD * DIM + (size_t)n * KD + k] = f2b(cw[i]);
    }
}

// X0b = bf16(w * lin_w + lin_b); thread = (node, dim pair)
__global__ void k_feat(const float* __restrict__ w, const float* __restrict__ lw,
                       const float* __restrict__ lb, ushort* __restrict__ Ab) {
    int i = blockIdx.x * 256 + threadIdx.x;
    if (i < NN * 64) {
        int n = i >> 6, dp = i & 63;
        float wn = w[n];
        ushort2 ub;
        ub.x = f2b(wn * lw[2 * dp] + lb[2 * dp]);
        ub.y = f2b(wn * lw[2 * dp + 1] + lb[2 * dp + 1]);
        ((ushort2*)(Ab + (size_t)n * DIM))[dp] = ub;
    }
}

// Layer-1 gather1 via rank-1 structure of X0 = w*lin_w + lin_b:
// sum_e w_e*X0[s] = (sum w_e*w[s])*lin_w + (sum w_e)*lin_b  -> scalar reductions.
// Qb[n] = bf16( -( sA*lw + sB*lb + X0[n]/deg ) ), X0[n] exact fp32.
__global__ __launch_bounds__(256) void k_gather1_l1(
        const float* __restrict__ w, const float* __restrict__ lw,
        const float* __restrict__ lb, const int* __restrict__ offs,
        const int* __restrict__ csr_src, const float* __restrict__ dinv,
        ushort* __restrict__ Qb) {
    int n = blockIdx.x * 4 + (threadIdx.x >> 6);
    int lane = threadIdx.x & 63;
    int j0 = offs[n], j1 = offs[n + 1];
    float dn = dinv[n];
    float sA = 0.f, sB = 0.f;
    for (int j = j0 + lane; j < j1; j += 64) {
        int s = csr_src[j];
        float ds = dinv[s];
        sA = fmaf(ds, w[s], sA);
        sB += ds;
    }
#pragma unroll
    for (int off = 32; off > 0; off >>= 1) {
        sA += __shfl_down(sA, off, 64);
        sB += __shfl_down(sB, off, 64);
    }
    sA = __shfl(sA, 0, 64) * dn;
    sB = __shfl(sB, 0, 64) * dn;
    float id = dn * dn;
    float wn = w[n];
    float lw0 = lw[2 * lane], lw1 = lw[2 * lane + 1];
    float lb0 = lb[2 * lane], lb1 = lb[2 * lane + 1];
    float x0a = wn * lw0 + lb0, x0b = wn * lw1 + lb1;
    ushort2 ub;
    ub.x = f2b(-(sA * lw0 + sB * lb0 + x0a * id));
    ub.y = f2b(-(sA * lw1 + sB * lb1 + x0b * id));
    ((ushort2*)(Qb + (size_t)n * DIM))[lane] = ub;
}

// Wave-per-node gather, bf16 rows. Lane owns dims {2*lane, 2*lane+1}.
// Qb[n] = bf16( -( sum w_e*Xb[src] + Xb[n]/deg ) )
__global__ __launch_bounds__(256) void k_gather1(
        const ushort* __restrict__ Xb, const int* __restrict__ offs,
        const int* __restrict__ csr_src, const float* __restrict__ dinv,
        ushort* __restrict__ Qb) {
    int n = blockIdx.x * 4 + (threadIdx.x >> 6);
    int lane = threadIdx.x & 63;
    int j0 = offs[n], j1 = offs[n + 1];
    float dn = dinv[n];
    float a0 = 0.f, a1 = 0.f;
    const uint* Xu = (const uint*)Xb;
    for (int base = j0; base < j1; base += 64) {
        int m = j1 - base; if (m > 64) m = 64;
        int s = 0; float wv = 0.f;
        if (lane < m) { s = csr_src[base + lane]; wv = dinv[s] * dn; }
        int t = 0;
        for (; t + 4 <= m; t += 4) {
            int s0 = __shfl(s, t, 64),     s1 = __shfl(s, t + 1, 64);
            int s2 = __shfl(s, t + 2, 64), s3 = __shfl(s, t + 3, 64);
            float w0 = __shfl(wv, t, 64),     w1 = __shfl(wv, t + 1, 64);
            float w2 = __shfl(wv, t + 2, 64), w3 = __shfl(wv, t + 3, 64);
            uint u0 = Xu[(size_t)s0 * 64 + lane];
            uint u1 = Xu[(size_t)s1 * 64 + lane];
            uint u2 = Xu[(size_t)s2 * 64 + lane];
            uint u3 = Xu[(size_t)s3 * 64 + lane];
            a0 = fmaf(w0, blo(u0), a0); a1 = fmaf(w0, bhi(u0), a1);
            a0 = fmaf(w1, blo(u1), a0); a1 = fmaf(w1, bhi(u1), a1);
            a0 = fmaf(w2, blo(u2), a0); a1 = fmaf(w2, bhi(u2), a1);
            a0 = fmaf(w3, blo(u3), a0); a1 = fmaf(w3, bhi(u3), a1);
        }
        for (; t < m; ++t) {
            int ss = __shfl(s, t, 64);
            float ww = __shfl(wv, t, 64);
            uint u = Xu[(size_t)ss * 64 + lane];
            a0 = fmaf(ww, blo(u), a0); a1 = fmaf(ww, bhi(u), a1);
        }
    }
    float id = dn * dn;
    uint un = ((const uint*)Xb)[(size_t)n * 64 + lane];
    ushort2 ub;
    ub.x = f2b(-(a0 + blo(un) * id));
    ub.y = f2b(-(a1 + bhi(un) * id));
    ((ushort2*)(Qb + (size_t)n * DIM))[lane] = ub;
}

// Rb[n] = bf16( -2*( sum w_e*X1b[src] + X1b[n]/deg ) - X0b[n] )
__global__ __launch_bounds__(256) void k_gather2(
        const ushort* __restrict__ X1b, const ushort* __restrict__ X0b,
        const int* __restrict__ offs, const int* __restrict__ csr_src,
        const float* __restrict__ dinv, ushort* __restrict__ Rb) {
    int n = blockIdx.x * 4 + (threadIdx.x >> 6);
    int lane = threadIdx.x & 63;
    int j0 = offs[n], j1 = offs[n + 1];
    float dn = dinv[n];
    float a0 = 0.f, a1 = 0.f;
    const uint* Xu = (const uint*)X1b;
    for (int base = j0; base < j1; base += 64) {
        int m = j1 - base; if (m > 64) m = 64;
        int s = 0; float wv = 0.f;
        if (lane < m) { s = csr_src[base + lane]; wv = dinv[s] * dn; }
        int t = 0;
        for (; t + 4 <= m; t += 4) {
            int s0 = __shfl(s, t, 64),     s1 = __shfl(s, t + 1, 64);
            int s2 = __shfl(s, t + 2, 64), s3 = __shfl(s, t + 3, 64);
            float w0 = __shfl(wv, t, 64),     w1 = __shfl(wv, t + 1, 64);
            float w2 = __shfl(wv, t + 2, 64), w3 = __shfl(wv, t + 3, 64);
            uint u0 = Xu[(size_t)s0 * 64 + lane];
            uint u1 = Xu[(size_t)s1 * 64 + lane];
            uint u2 = Xu[(size_t)s2 * 64 + lane];
            uint u3 = Xu[(size_t)s3 * 64 + lane];
            a0 = fmaf(w0, blo(u0), a0); a1 = fmaf(w0, bhi(u0), a1);
            a0 = fmaf(w1, blo(u1), a0); a1 = fmaf(w1, bhi(u1), a1);
            a0 = fmaf(w2, blo(u2), a0); a1 = fmaf(w2, bhi(u2), a1);
            a0 = fmaf(w3, blo(u3), a0); a1 = fmaf(w3, bhi(u3), a1);
        }
        for (; t < m; ++t) {
            int ss = __shfl(s, t, 64);
            float ww = __shfl(wv, t, 64);
            uint u = Xu[(size_t)ss * 64 + lane];
            a0 = fmaf(ww, blo(u), a0); a1 = fmaf(ww, bhi(u), a1);
        }
    }
    float id = dn * dn;
    uint u1n = ((const uint*)X1b)[(size_t)n * 64 + lane];
    uint u0n = ((const uint*)X0b)[(size_t)n * 64 + lane];
    ushort2 ub;
    ub.x = f2b(-2.f * (a0 + blo(u1n) * id) - blo(u0n));
    ub.y = f2b(-2.f * (a1 + bhi(u1n) * id) - bhi(u0n));
    ((ushort2*)(Rb + (size_t)n * DIM))[lane] = ub;
}

// MFMA GEMM: outb = bf16(relu([X0|X1|X2] @ W + bias)). 128x128 per block,
// 4 waves each 64x64 quadrant as 4x4 16x16x32 bf16 MFMA tiles. bf16 out only.
// Aliasing (outb == X0b) safe: block reads only its own 128 rows, writes last.
__global__ __launch_bounds__(256) void k_gemm(
        const ushort* __restrict__ X0b, const ushort* __restrict__ X1b,
        const ushort* __restrict__ X2b, const ushort* __restrict__ Wt,
        const float* __restrict__ bias, ushort* __restrict__ outb) {
    __shared__ ushort As[128 * PADK];
    __shared__ ushort Bs[128 * PADK];
    int tid = threadIdx.x;
    int nbase = blockIdx.x * 128;
    int wave = tid >> 6, lane = tid & 63;
    int wr = wave >> 1, wc = wave & 1;
    int l15 = lane & 15, quad = lane >> 4;

    float4v acc[4][4];
#pragma unroll
    for (int i = 0; i < 4; ++i)
#pragma unroll
        for (int j = 0; j < 4; ++j) acc[i][j] = (float4v)0.f;

    int srow = tid >> 1, shalf = tid & 1;
    int gm = nbase + srow; if (gm >= NN) gm = NN - 1;

    for (int c = 0; c < 12; ++c) {
        int part = c >> 2;
        int k0 = (c & 3) * 32;
        const ushort* Xp = (part == 0) ? X0b : ((part == 1) ? X1b : X2b);
        const uint4* ga = (const uint4*)(Xp + (size_t)gm * DIM + k0 + shalf * 16);
        uint4 a0 = ga[0], a1 = ga[1];
        const uint4* gb = (const uint4*)(Wt + (size_t)srow * KD + c * 32 + shalf * 16);
        uint4 b0 = gb[0], b1 = gb[1];
        __syncthreads();
        uint4* pa = (uint4*)(As + srow * PADK + shalf * 16);
        pa[0] = a0; pa[1] = a1;
        uint4* pb = (uint4*)(Bs + srow * PADK + shalf * 16);
        pb[0] = b0; pb[1] = b1;
        __syncthreads();
        short8 af[4], bf[4];
#pragma unroll
        for (int i = 0; i < 4; ++i) {
            af[i] = *(const short8*)(As + (wr * 64 + i * 16 + l15) * PADK + quad * 8);
            bf[i] = *(const short8*)(Bs + (wc * 64 + i * 16 + l15) * PADK + quad * 8);
        }
#pragma unroll
        for (int i = 0; i < 4; ++i)
#pragma unroll
            for (int j = 0; j < 4; ++j)
                acc[i][j] = __builtin_amdgcn_mfma_f32_16x16x32_bf16(
                    af[i], bf[j], acc[i][j], 0, 0, 0);
    }

    float bv[4];
#pragma unroll
    for (int j = 0; j < 4; ++j) bv[j] = bias[wc * 64 + j * 16 + l15];
#pragma unroll
    for (int i = 0; i < 4; ++i) {
#pragma unroll
        for (int r = 0; r < 4; ++r) {
            int node = nbase + wr * 64 + i * 16 + quad * 4 + r;
            if (node < NN) {
#pragma unroll
                for (int j = 0; j < 4; ++j) {
                    int col = wc * 64 + j * 16 + l15;
                    outb[(size_t)node * DIM + col] =
                        f2b(fmaxf(acc[i][j][r] + bv[j], 0.f));
                }
            }
        }
    }
}

// Last-layer GEMM with fused prediction head:
// logits[n] = relu(row) . pred_w + pred_b, relu applied per element in-register.
__global__ __launch_bounds__(256) void k_gemm_pred(
        const ushort* __restrict__ X0b, const ushort* __restrict__ X1b,
        const ushort* __restrict__ X2b, const ushort* __restrict__ Wt,
        const float* __restrict__ bias, const float* __restrict__ pw,
        const float* __restrict__ pb, float* __restrict__ logits) {
    __shared__ ushort As[128 * PADK];
    __shared__ ushort Bs[128 * PADK];
    __shared__ float lsum[128];
    int tid = threadIdx.x;
    int nbase = blockIdx.x * 128;
    int wave = tid >> 6, lane = tid & 63;
    int wr = wave >> 1, wc = wave & 1;
    int l15 = lane & 15, quad = lane >> 4;

    float4v acc[4][4];
#pragma unroll
    for (int i = 0; i < 4; ++i)
#pragma unroll
        for (int j = 0; j < 4; ++j) acc[i][j] = (float4v)0.f;

    int srow = tid >> 1, shalf = tid & 1;
    int gm = nbase + srow; if (gm >= NN) gm = NN - 1;

    for (int c = 0; c < 12; ++c) {
        int part = c >> 2;
        int k0 = (c & 3) * 32;
        const ushort* Xp = (part == 0) ? X0b : ((part == 1) ? X1b : X2b);
        const uint4* ga = (const uint4*)(Xp + (size_t)gm * DIM + k0 + shalf * 16);
        uint4 a0 = ga[0], a1 = ga[1];
        const uint4* gb = (const uint4*)(Wt + (size_t)srow * KD + c * 32 + shalf * 16);
        uint4 b0 = gb[0], b1 = gb[1];
        __syncthreads();
        uint4* pa = (uint4*)(As + srow * PADK + shalf * 16);
        pa[0] = a0; pa[1] = a1;
        uint4* pb2 = (uint4*)(Bs + srow * PADK + shalf * 16);
        pb2[0] = b0; pb2[1] = b1;
        __syncthreads();
        short8 af[4], bf[4];
#pragma unroll
        for (int i = 0; i < 4; ++i) {
            af[i] = *(const short8*)(As + (wr * 64 + i * 16 + l15) * PADK + quad * 8);
            bf[i] = *(const short8*)(Bs + (wc * 64 + i * 16 + l15) * PADK + quad * 8);
        }
#pragma unroll
        for (int i = 0; i < 4; ++i)
#pragma unroll
            for (int j = 0; j < 4; ++j)
                acc[i][j] = __builtin_amdgcn_mfma_f32_16x16x32_bf16(
                    af[i], bf[j], acc[i][j], 0, 0, 0);
    }

    __syncthreads();
    if (tid < 128) lsum[tid] = 0.f;
    __syncthreads();
    float bv[4], pwv[4];
#pragma unroll
    for (int j = 0; j < 4; ++j) {
        int col = wc * 64 + j * 16 + l15;
        bv[j] = bias[col];
        pwv[j] = pw[col];
    }
#pragma unroll
    for (int i = 0; i < 4; ++i) {
#pragma unroll
        for (int r = 0; r < 4; ++r) {
            float local = 0.f;
#pragma unroll
            for (int j = 0; j < 4; ++j)
                local = fmaf(fmaxf(acc[i][j][r] + bv[j], 0.f), pwv[j], local);
            local += __shfl_xor(local, 1, 64);
            local += __shfl_xor(local, 2, 64);
            local += __shfl_xor(local, 4, 64);
            local += __shfl_xor(local, 8, 64);
            if (l15 == 0)
                atomicAdd(&lsum[wr * 64 + i * 16 + quad * 4 + r], local);
        }
    }
    __syncthreads();
    if (tid < 128) {
        int node = nbase + tid;
        if (node < NN) logits[node] = lsum[tid] + pb[0];
    }
}

extern "C" void kernel_launch(void* const* d_in, const int* in_sizes, int n_in,
                              void* d_out, int out_size, void* d_ws, size_t ws_size,
                              hipStream_t stream) {
    int i_weights = 0, i_src = 1, i_dst = 2, i_lw = 3, i_lb = 4,
        i_cw = 5, i_cb = 6, i_pw = 7, i_pb = 8;
    {
        int seen600k = 0, seen128 = 0;
        for (int i = 0; i < n_in; ++i) {
            int s = in_sizes[i];
            if (s == 50000) i_weights = i;
            else if (s == 600000) { if (seen600k == 0) i_src = i; else i_dst = i; ++seen600k; }
            else if (s == 128) { if (seen128 == 0) i_lw = i; else if (seen128 == 1) i_lb = i; else i_pw = i; ++seen128; }
            else if (s == 147456) i_cw = i;
            else if (s == 384) i_cb = i;
            else if (s == 1) i_pb = i;
        }
    }
    const float* weights = (const float*)d_in[i_weights];
    const int*   src     = (const int*)d_in[i_src];
    const int*   dst     = (const int*)d_in[i_dst];
    const float* lin_w   = (const float*)d_in[i_lw];
    const float* lin_b   = (const float*)d_in[i_lb];
    const float* cheb_w  = (const float*)d_in[i_cw];
    const float* cheb_b  = (const float*)d_in[i_cb];
    const float* pred_w  = (const float*)d_in[i_pw];
    const float* pred_b  = (const float*)d_in[i_pb];
    float* out = (float*)d_out;

    // Workspace (~45 MB; ws_size observed ~268 MB):
    float* ws      = (float*)d_ws;
    float* dinv    = ws;                           // 50048 floats
    int*   offs    = (int*)(ws + 50048);           // 50056 ints
    int*   csr_src = offs + 50056;                 // 600000 ints
    int*   cnt     = csr_src + 600000;             // 50176 ints
    int*   incl    = cnt + 50176;                  // 50176 ints
    int*   bsums   = incl + 50176;                 // 256 ints
    ushort* Pb     = (ushort*)(bsums + 256);       // 6.4M bf16 (X0)
    ushort* Qb     = Pb + (size_t)NN * DIM;        // 6.4M bf16 (X1)
    ushort* Rb     = Qb + (size_t)NN * DIM;        // 6.4M bf16 (X2)
    ushort* Wtb    = Rb + (size_t)NN * DIM;        // 442368 bf16

    // --- CSR build + weight transpose (once) ---
    k_zero<<<49, 256, 0, stream>>>((float*)cnt, 12544);
    k_hist<<<2344, 256, 0, stream>>>(dst, cnt);
    k_dinv<<<196, 256, 0, stream>>>(cnt, dinv);
    k_scan1<<<196, 256, 0, stream>>>(cnt, incl, bsums);
    k_scan2<<<1, 256, 0, stream>>>(bsums);
    k_scan3<<<196, 256, 0, stream>>>(cnt, incl, bsums, offs);
    k_fill<<<2344, 256, 0, stream>>>(src, dst, incl, csr_src);
    k_wt<<<576, 256, 0, stream>>>(cheb_w, Wtb);

    // --- network ---
    k_feat<<<12500, 256, 0, stream>>>(weights, lin_w, lin_b, Pb);
    // layer 1 (rank-1 gather1)
    k_gather1_l1<<<12500, 256, 0, stream>>>(weights, lin_w, lin_b, offs, csr_src, dinv, Qb);
    k_gather2<<<12500, 256, 0, stream>>>(Qb, Pb, offs, csr_src, dinv, Rb);
    k_gemm<<<391, 256, 0, stream>>>(Pb, Qb, Rb, Wtb, cheb_b, Pb);
    // layer 2
    k_gather1<<<12500, 256, 0, stream>>>(Pb, offs, csr_src, dinv, Qb);
    k_gather2<<<12500, 256, 0, stream>>>(Qb, Pb, offs, csr_src, dinv, Rb);
    k_gemm<<<391, 256, 0, stream>>>(Pb, Qb, Rb, Wtb + (size_t)KD * DIM,
                                    cheb_b + DIM, Pb);
    // layer 3 (fused prediction head)
    k_gather1<<<12500, 256, 0, stream>>>(Pb, offs, csr_src, dinv, Qb);
    k_gather2<<<12500, 256, 0, stream>>>(Qb, Pb, offs, csr_src, dinv, Rb);
    k_gemm_pred<<<391, 256, 0, stream>>>(Pb, Qb, Rb, Wtb + (size_t)2 * KD * DIM,
                                         cheb_b + 2 * DIM, pred_w, pred_b, out);
}